// Round 10
// baseline (476.483 us; speedup 1.0000x reference)
//
#include <hip/hip_runtime.h>
#include <hip/hip_bf16.h>
#include <math.h>

#define BB 8
#define NN 1024
#define KNNK 20
#define LDC 512

typedef __attribute__((ext_vector_type(8))) short bfrag8;
typedef __attribute__((ext_vector_type(4))) float facc4;
typedef __attribute__((ext_vector_type(2))) float v2f;

struct bh8 { __hip_bfloat16 h[8]; };

__device__ __forceinline__ bh8 cvt8(float4 a, float4 b) {
    bh8 v;
    v.h[0] = __float2bfloat16(a.x); v.h[1] = __float2bfloat16(a.y);
    v.h[2] = __float2bfloat16(a.z); v.h[3] = __float2bfloat16(a.w);
    v.h[4] = __float2bfloat16(b.x); v.h[5] = __float2bfloat16(b.y);
    v.h[6] = __float2bfloat16(b.z); v.h[7] = __float2bfloat16(b.w);
    return v;
}

// Batcher sorting network for 16 elements (descending)
static constexpr unsigned char s_CA[63] = {
    0,2,4,6,8,10,12,14,
    0,1,4,5,8,9,12,13,
    1,5,9,13,
    0,1,2,3,8,9,10,11,
    2,3,10,11,
    1,3,5,9,11,13,
    0,1,2,3,4,5,6,7,
    4,5,6,7,
    2,3,6,7,10,11,
    1,3,5,7,9,11,13};
static constexpr unsigned char s_CB[63] = {
    1,3,5,7,9,11,13,15,
    2,3,6,7,10,11,14,15,
    2,6,10,14,
    4,5,6,7,12,13,14,15,
    4,5,12,13,
    2,4,6,10,12,14,
    8,9,10,11,12,13,14,15,
    8,9,10,11,
    4,5,8,9,12,13,
    2,4,6,8,10,12,14};

// ---- DPP wave64 max reduce: 6 VALU-pipe steps, no ds_bpermute on the chain ----
template<int CTRL, int RMASK>
__device__ __forceinline__ float fmax_dpp(float x) {
    int xi = __float_as_int(x);
    int yi = __builtin_amdgcn_update_dpp(xi, xi, CTRL, RMASK, 0xF, false);
    return fmaxf(x, __int_as_float(yi));
}

__device__ __forceinline__ float wave_max64(float x) {
    x = fmax_dpp<0x121, 0xF>(x);   // row_ror:1
    x = fmax_dpp<0x122, 0xF>(x);   // row_ror:2
    x = fmax_dpp<0x124, 0xF>(x);   // row_ror:4
    x = fmax_dpp<0x128, 0xF>(x);   // row_ror:8  -> each lane = max of its row(16)
    x = fmax_dpp<0x142, 0xA>(x);   // row_bcast15 -> rows 1,3 combine with rows 0,2
    x = fmax_dpp<0x143, 0xC>(x);   // row_bcast31 -> lane63 = wave max
    return __int_as_float(__builtin_amdgcn_readlane(__float_as_int(x), 63));
}

// ---------------- top-20 selection, 2 queries/wave (stage 1) ----------------
__device__ __forceinline__ void select20_pf(float (*dist)[1024],
                                            int q0, int w, int lane,
                                            int* __restrict__ idxout) {
    float d[2][16];
    int   sl[2][16];
#pragma unroll
    for (int qi = 0; qi < 2; qi++) {
        int row = w * 2 + qi;
#pragma unroll
        for (int j = 0; j < 16; j++) { d[qi][j] = dist[row][lane + 64 * j]; sl[qi][j] = j; }
    }
#pragma unroll
    for (int c = 0; c < 63; c++) {
        const int a = s_CA[c], bq = s_CB[c];
#pragma unroll
        for (int qi = 0; qi < 2; qi++) {
            bool sw = d[qi][a] < d[qi][bq];
            float dmx = sw ? d[qi][bq] : d[qi][a];
            float dmn = sw ? d[qi][a]  : d[qi][bq];
            d[qi][a] = dmx; d[qi][bq] = dmn;
            int smx = sw ? sl[qi][bq] : sl[qi][a];
            int smn = sw ? sl[qi][a]  : sl[qi][bq];
            sl[qi][a] = smx; sl[qi][bq] = smn;
        }
    }
    unsigned long long slp[2];
#pragma unroll
    for (int qi = 0; qi < 2; qi++) {
        int row = w * 2 + qi;
#pragma unroll
        for (int j = 0; j < 16; j++) dist[row][j * 64 + lane] = d[qi][j];
        unsigned long long p = 0;
#pragma unroll
        for (int j = 0; j < 16; j++) p |= (unsigned long long)sl[qi][j] << (4 * j);
        slp[qi] = p;
    }
    float head[2] = {d[0][0], d[1][0]};
    float pf[2]   = {d[0][1], d[1][1]};
    int   ptr[2]  = {2, 2};
    for (int t = 0; t < KNNK; t++) {
#pragma unroll
        for (int qi = 0; qi < 2; qi++) {
            int row = w * 2 + qi;
            float bv = wave_max64(head[qi]);
            unsigned long long ball = __ballot(head[qi] == bv);
            int wl = (int)__builtin_ctzll(ball);
            bool win = (lane == wl);
            if (win) {
                idxout[(q0 + row) * KNNK + t] = (int)(slp[qi] & 15ull) * 64 + lane;
            }
            head[qi] = win ? pf[qi] : head[qi];
            slp[qi]  = win ? (slp[qi] >> 4) : slp[qi];
            if (win) {
                int p = ptr[qi];
                pf[qi] = (p < 16) ? dist[row][p * 64 + lane] : -INFINITY;
                ptr[qi] = p + 1;
            }
        }
    }
}

// ---------------- top-20 selection, 4 queries/wave (stages 2-4, 16 q/block) ----------------
__device__ __forceinline__ void select20_q4(float (*dist)[1024],
                                            int q0, int w, int lane,
                                            int* __restrict__ idxout) {
    unsigned long long slp[4];
    float head[4], pf[4];
    int   ptr[4];
#pragma unroll
    for (int qi = 0; qi < 4; qi++) {
        int row = w * 4 + qi;
        float d[16];
        int   sl[16];
#pragma unroll
        for (int j = 0; j < 16; j++) { d[j] = dist[row][lane + 64 * j]; sl[j] = j; }
#pragma unroll
        for (int c = 0; c < 63; c++) {
            const int a = s_CA[c], bq = s_CB[c];
            bool sw = d[a] < d[bq];
            float dmx = sw ? d[bq] : d[a];
            float dmn = sw ? d[a]  : d[bq];
            d[a] = dmx; d[bq] = dmn;
            int smx = sw ? sl[bq] : sl[a];
            int smn = sw ? sl[a]  : sl[bq];
            sl[a] = smx; sl[bq] = smn;
        }
#pragma unroll
        for (int j = 0; j < 16; j++) dist[row][j * 64 + lane] = d[j];
        unsigned long long p = 0;
#pragma unroll
        for (int j = 0; j < 16; j++) p |= (unsigned long long)sl[j] << (4 * j);
        slp[qi]  = p;
        head[qi] = d[0];
        pf[qi]   = d[1];
        ptr[qi]  = 2;
    }
    for (int t = 0; t < KNNK; t++) {
#pragma unroll
        for (int qi = 0; qi < 4; qi++) {
            int row = w * 4 + qi;
            float bv = wave_max64(head[qi]);
            unsigned long long ball = __ballot(head[qi] == bv);
            int wl = (int)__builtin_ctzll(ball);
            bool win = (lane == wl);
            if (win) {
                idxout[(q0 + row) * KNNK + t] = (int)(slp[qi] & 15ull) * 64 + lane;
            }
            head[qi] = win ? pf[qi] : head[qi];
            slp[qi]  = win ? (slp[qi] >> 4) : slp[qi];
            if (win) {
                int p = ptr[qi];
                pf[qi] = (p < 16) ? dist[row][p * 64 + lane] : -INFINITY;
                ptr[qi] = p + 1;
            }
        }
    }
}

// r1 zeroing helper (done by one designated block of the kernel preceding the gather)
__device__ __forceinline__ void zero_r1(float* r1s, float* r1q, int O, int tid) {
    for (int i = tid; i < 32 * O; i += 256) { r1s[i] = 0.f; r1q[i] = 0.f; }
}

// ---------------- fused kNN stage 1 (C=3) + stage-1 z-gemm, 8 queries/block ----------------
__global__ __launch_bounds__(256, 4) void knn3_fused(const float* __restrict__ x,
                                                     const float* __restrict__ w1,
                                                     float* __restrict__ zf,
                                                     int* __restrict__ idxout,
                                                     float* __restrict__ r1s, float* __restrict__ r1q) {
    __shared__ float dist[8][1024];
    int tid = threadIdx.x;
    int q0 = (blockIdx.x & 7) * 1024 + (blockIdx.x >> 3) * 8;   // XCD swizzle
    int b = q0 >> 10;
    if (blockIdx.x == 0) zero_r1(r1s, r1q, 64, tid);
    const float* xb = x + (size_t)b * NN * 3;
    int lane = tid & 63, w = tid >> 6;
    float qx[8], qy[8], qz[8];
#pragma unroll
    for (int q = 0; q < 8; q++) {
        const float* qr = xb + (size_t)((q0 & (NN - 1)) + q) * 3;
        qx[q] = qr[0]; qy[q] = qr[1]; qz[q] = qr[2];
    }
#pragma unroll
    for (int cq = 0; cq < 4; cq++) {
        int cand = w * 256 + cq * 64 + lane;
        const float* cr = xb + (size_t)cand * 3;
        float cx = cr[0], cy = cr[1], cz = cr[2];
        float sqc = cx * cx + cy * cy + cz * cz;
#pragma unroll
        for (int q = 0; q < 8; q++) {
            float d = qx[q] * cx + qy[q] * cy + qz[q] * cz;
            dist[q][cand] = 2.f * d - sqc;
        }
    }
    for (int i = tid; i < 8 * 128; i += 256) {
        int lq = i >> 7, j = i & 127;
        const float* wr = w1 + (j < 64 ? j * 6 : (j - 64) * 6 + 3);
        const float* xr = x + (size_t)(q0 + lq) * 3;
        zf[(size_t)(q0 + lq) * 128 + j] = wr[0] * xr[0] + wr[1] * xr[1] + wr[2] * xr[2];
    }
    __syncthreads();
    select20_pf(dist, q0, w, lane, idxout);
}

// ---------------- knn core (stages 2-4): 16 queries/block, wave-uniform query loads ----------------
template<int C>
__device__ __forceinline__ void knn_body16(const float* __restrict__ xT,
                                           const float* __restrict__ sqn,
                                           int* __restrict__ idxout,
                                           float (*dist)[1024], int knnBlk) {
    int tid = threadIdx.x;
    int q0 = (knnBlk & 7) * 1024 + (knnBlk >> 3) * 16;          // XCD swizzle
    int b = q0 >> 10;
    int lane = tid & 63, w = tid >> 6;
    int cand0 = w * 256 + 4 * lane;
    const float* xTb = xT + (size_t)b * C * 1024;
    const float* qrow = xTb + (q0 & (NN - 1));                  // block-uniform base
    float4 sq4 = *(const float4*)(sqn + b * NN + cand0);
    v2f acc2[4][8];
#pragma unroll
    for (int j = 0; j < 4; j++)
#pragma unroll
        for (int p = 0; p < 8; p++) acc2[j][p] = (v2f){0.f, 0.f};
    for (int cg = 0; cg < C / 4; cg++) {
        float4 rch[4];
#pragma unroll
        for (int c = 0; c < 4; c++)
            rch[c] = *(const float4*)(xTb + (size_t)(4 * cg + c) * 1024 + cand0);
#pragma unroll
        for (int c = 0; c < 4; c++) {
            const float* qr = qrow + (size_t)(4 * cg + c) * 1024;
            float4 qa = *(const float4*)qr;                     // uniform -> s_load (16 queries)
            float4 qb = *(const float4*)(qr + 4);
            float4 qc = *(const float4*)(qr + 8);
            float4 qd = *(const float4*)(qr + 12);
            v2f qp[8] = {{qa.x, qa.y}, {qa.z, qa.w}, {qb.x, qb.y}, {qb.z, qb.w},
                         {qc.x, qc.y}, {qc.z, qc.w}, {qd.x, qd.y}, {qd.z, qd.w}};
            float rj[4] = {rch[c].x, rch[c].y, rch[c].z, rch[c].w};
#pragma unroll
            for (int j = 0; j < 4; j++) {
                v2f rr = {rj[j], rj[j]};
#pragma unroll
                for (int p = 0; p < 8; p++) acc2[j][p] += rr * qp[p];
            }
        }
    }
#pragma unroll
    for (int p = 0; p < 8; p++)
#pragma unroll
        for (int half = 0; half < 2; half++) {
            int q = 2 * p + half;
            float4 dv;
            dv.x = 2.f * acc2[0][p][half] - sq4.x;
            dv.y = 2.f * acc2[1][p][half] - sq4.y;
            dv.z = 2.f * acc2[2][p][half] - sq4.z;
            dv.w = 2.f * acc2[3][p][half] - sq4.w;
            *(float4*)&dist[q][cand0] = dv;
        }
    __syncthreads();
    select20_q4(dist, q0, w, lane, idxout);
}

// ---------------- FAT kernel stages 2-3: knn 16q (blocks<512) + zgemm (blocks>=512) ----------------
template<int C, int ZO2>
__global__ __launch_bounds__(256, 2) void knnz_fat(const float* __restrict__ xT,
                                                   const float* __restrict__ xt, int off,
                                                   const float* __restrict__ sqn,
                                                   int* __restrict__ idxout,
                                                   const float* __restrict__ w,
                                                   float* __restrict__ zf,
                                                   float* __restrict__ r1s, float* __restrict__ r1q,
                                                   int Onext) {
    __shared__ float dist[16][1024];
    int tid = threadIdx.x;
    if ((int)blockIdx.x < BB * NN / 16) {
        knn_body16<C>(xT, sqn, idxout, dist, blockIdx.x);
        return;
    }
    // ---- zgemm path ----
    constexpr int ZO = ZO2 / 2;
    int zblk = blockIdx.x - BB * NN / 16;
    if (zblk == 0) zero_r1(r1s, r1q, Onext, tid);
    float (*xs)[C] = (float (*)[C])&dist[0][0];
    int p0 = zblk * 16;
    for (int j = tid; j < 16 * (C / 4); j += 256) {
        int p = j / (C / 4), c4 = j % (C / 4);
        *(float4*)&xs[p][4 * c4] = *(const float4*)(xt + (size_t)(p0 + p) * LDC + off + 4 * c4);
    }
    __syncthreads();
    for (int j = tid; j < ZO2; j += 256) {
        const float* wr = w + (j < ZO ? (size_t)j * 2 * C : (size_t)(j - ZO) * 2 * C + C);
        float acc[16];
#pragma unroll
        for (int p = 0; p < 16; p++) acc[p] = 0.f;
        for (int c4 = 0; c4 < C / 4; c4++) {
            float4 wv = *(const float4*)(wr + 4 * c4);
#pragma unroll
            for (int p = 0; p < 16; p++) {
                float4 xv = *(const float4*)&xs[p][4 * c4];
                acc[p] += wv.x * xv.x + wv.y * xv.y + wv.z * xv.z + wv.w * xv.w;
            }
        }
#pragma unroll
        for (int p = 0; p < 16; p++) zf[(size_t)(p0 + p) * ZO2 + j] = acc[p];
    }
}

// ---------------- FAT stage 4: knn<128> 16q (blocks<512) + bf16 MFMA zgemm (blocks>=512) ----------------
__global__ __launch_bounds__(256, 2) void knnz4_fat(const float* __restrict__ xT,
                                                    const float* __restrict__ sqn,
                                                    int* __restrict__ idxout,
                                                    const float* __restrict__ xtcat,
                                                    const float* __restrict__ w4,
                                                    __hip_bfloat16* __restrict__ zf4,
                                                    float* __restrict__ r1s, float* __restrict__ r1q) {
    __shared__ __align__(16) char smem[65536];
    int tid = threadIdx.x;
    if ((int)blockIdx.x < BB * NN / 16) {
        float (*dist)[1024] = (float (*)[1024])smem;
        if (blockIdx.x == 0) zero_r1(r1s, r1q, 256, tid);
        knn_body16<128>(xT, sqn, idxout, dist, blockIdx.x);
        return;
    }
    // ---- zgemm4 path (bf16 MFMA) ----
    __hip_bfloat16 (*A)[72] = (__hip_bfloat16 (*)[72])smem;
    __hip_bfloat16 (*W)[72] = (__hip_bfloat16 (*)[72])(smem + 18432);
    int zblk = blockIdx.x - BB * NN / 16;
    int mt = zblk >> 2, nt = zblk & 3;
    int lane = tid & 63, wvx = tid >> 6;
    int mw = wvx >> 1, nw = wvx & 1;
    int m0 = lane & 15, qd = lane >> 4;
    int r = tid & 127, hf = tid >> 7;
    facc4 acc[4][4];
    facc4 zz = {0.f, 0.f, 0.f, 0.f};
#pragma unroll
    for (int mi = 0; mi < 4; mi++)
#pragma unroll
        for (int ni = 0; ni < 4; ni++) acc[mi][ni] = zz;
    int j = nt * 128 + r;
    const float* wsrc = w4 + (j < 256 ? (size_t)j * 256 : (size_t)(j - 256) * 256 + 128);
    const float* asrc = xtcat + (size_t)(mt * 128 + r) * 512 + 128;
    for (int kc = 0; kc < 2; kc++) {
#pragma unroll
        for (int u = 0; u < 4; u++) {
            int c0 = kc * 64 + hf * 32 + 8 * u;
            float4 a0 = *(const float4*)(asrc + c0);
            float4 a1 = *(const float4*)(asrc + c0 + 4);
            *(bh8*)&A[r][hf * 32 + 8 * u] = cvt8(a0, a1);
            float4 w0 = *(const float4*)(wsrc + c0);
            float4 w1 = *(const float4*)(wsrc + c0 + 4);
            *(bh8*)&W[r][hf * 32 + 8 * u] = cvt8(w0, w1);
        }
        __syncthreads();
#pragma unroll
        for (int kk = 0; kk < 2; kk++) {
            bfrag8 af[4], bf[4];
#pragma unroll
            for (int mi = 0; mi < 4; mi++)
                af[mi] = *(const bfrag8*)&A[64 * mw + 16 * mi + m0][32 * kk + 8 * qd];
#pragma unroll
            for (int ni = 0; ni < 4; ni++)
                bf[ni] = *(const bfrag8*)&W[64 * nw + 16 * ni + m0][32 * kk + 8 * qd];
#pragma unroll
            for (int mi = 0; mi < 4; mi++)
#pragma unroll
                for (int ni = 0; ni < 4; ni++)
                    acc[mi][ni] = __builtin_amdgcn_mfma_f32_16x16x32_bf16(af[mi], bf[ni], acc[mi][ni], 0, 0, 0);
        }
        __syncthreads();
    }
#pragma unroll
    for (int mi = 0; mi < 4; mi++)
#pragma unroll
        for (int ni = 0; ni < 4; ni++)
#pragma unroll
            for (int rg = 0; rg < 4; rg++) {
                int row = mt * 128 + mw * 64 + mi * 16 + qd * 4 + rg;
                int col = nt * 128 + nw * 64 + ni * 16 + m0;
                zf4[(size_t)row * 512 + col] = __float2bfloat16(acc[mi][ni][rg]);
            }
}

// ---------------- gather + stats (fp32 zf, stages 1-3): in-block reduce + atomics ----------------
template<int O2>
__global__ __launch_bounds__(256) void gatherstats_k(const float* __restrict__ zf,
                                                     const int* __restrict__ idx,
                                                     float* __restrict__ ymax, float* __restrict__ ymin,
                                                     float* __restrict__ r1s, float* __restrict__ r1q) {
    constexpr int O = O2 / 2;
    __shared__ float red_s[4][O], red_q[4][O];
    int wv = threadIdx.x >> 6, lane = threadIdx.x & 63;
    int n = (blockIdx.x & 7) * 1024 + (blockIdx.x >> 3) * 4 + wv;   // XCD swizzle
    int b = n >> 10;
    const float* zbatch = zf + (size_t)b * NN * O2;
    int nb[KNNK];
#pragma unroll
    for (int k = 0; k < KNNK; k++) nb[k] = idx[n * KNNK + k];
#pragma unroll
    for (int ch = 0; ch < O / 64; ch++) {
        int o = ch * 64 + lane;
        float g[KNNK];
#pragma unroll
        for (int k = 0; k < KNNK; k++) g[k] = zbatch[(size_t)nb[k] * O2 + o];
        float mx = -INFINITY, mn = INFINITY, s = 0.f, ss = 0.f;
#pragma unroll
        for (int k = 0; k < KNNK; k++) {
            float v = g[k];
            mx = fmaxf(mx, v); mn = fminf(mn, v); s += v; ss += v * v;
        }
        float zn  = zf[(size_t)n * O2 + o];
        float zbn = zf[(size_t)n * O2 + O + o];
        float d = zbn - zn;
        mx += d; mn += d;
        ss = ss + 2.f * d * s + (float)KNNK * d * d;
        s  = s + (float)KNNK * d;
        ymax[(size_t)n * O + o] = mx;
        ymin[(size_t)n * O + o] = mn;
        red_s[wv][o] = s;
        red_q[wv][o] = ss;
    }
    __syncthreads();
    int bucket = blockIdx.x & 31;
    for (int o = threadIdx.x; o < O; o += 256) {
        float s4 = red_s[0][o] + red_s[1][o] + red_s[2][o] + red_s[3][o];
        float q4 = red_q[0][o] + red_q[1][o] + red_q[2][o] + red_q[3][o];
        atomicAdd(&r1s[(size_t)bucket * O + o], s4);
        atomicAdd(&r1q[(size_t)bucket * O + o], q4);
    }
}

// ---------------- gather + stats, bf16 zf4 (stage 4) ----------------
__global__ __launch_bounds__(256) void gatherstats4_k(const __hip_bfloat16* __restrict__ zf4,
                                                      const int* __restrict__ idx,
                                                      float* __restrict__ ymax, float* __restrict__ ymin,
                                                      float* __restrict__ r1s, float* __restrict__ r1q) {
    __shared__ float red_s[4][256], red_q[4][256];
    int wv = threadIdx.x >> 6, lane = threadIdx.x & 63;
    int n = (blockIdx.x & 7) * 1024 + (blockIdx.x >> 3) * 4 + wv;
    int b = n >> 10;
    const __hip_bfloat16* zbatch = zf4 + (size_t)b * NN * 512;
    int nb[KNNK];
#pragma unroll
    for (int k = 0; k < KNNK; k++) nb[k] = idx[n * KNNK + k];
#pragma unroll
    for (int ch = 0; ch < 4; ch++) {
        int o = ch * 64 + lane;
        float g[KNNK];
#pragma unroll
        for (int k = 0; k < KNNK; k++) g[k] = __bfloat162float(zbatch[(size_t)nb[k] * 512 + o]);
        float mx = -INFINITY, mn = INFINITY, s = 0.f, ss = 0.f;
#pragma unroll
        for (int k = 0; k < KNNK; k++) {
            float v = g[k];
            mx = fmaxf(mx, v); mn = fminf(mn, v); s += v; ss += v * v;
        }
        float zn  = __bfloat162float(zf4[(size_t)n * 512 + o]);
        float zbn = __bfloat162float(zf4[(size_t)n * 512 + 256 + o]);
        float d = zbn - zn;
        mx += d; mn += d;
        ss = ss + 2.f * d * s + (float)KNNK * d * d;
        s  = s + (float)KNNK * d;
        ymax[(size_t)n * 256 + o] = mx;
        ymin[(size_t)n * 256 + o] = mn;
        red_s[wv][o] = s;
        red_q[wv][o] = ss;
    }
    __syncthreads();
    int bucket = blockIdx.x & 31;
    for (int o = threadIdx.x; o < 256; o += 256) {
        float s4 = red_s[0][o] + red_s[1][o] + red_s[2][o] + red_s[3][o];
        float q4 = red_q[0][o] + red_q[1][o] + red_q[2][o] + red_q[3][o];
        atomicAdd(&r1s[(size_t)bucket * 256 + o], s4);
        atomicAdd(&r1q[(size_t)bucket * 256 + o], q4);
    }
}

// ---------------- BN+lrelu epilogue + transpose + |c|^2 + bf16 copy, s/t computed in-block ----------------
template<int O>
__global__ __launch_bounds__(256) void epitrans2_k(const float* __restrict__ ymax, const float* __restrict__ ymin,
                                                   const float* __restrict__ r1s, const float* __restrict__ r1q,
                                                   const float* __restrict__ g, const float* __restrict__ beta,
                                                   double invM,
                                                   float* __restrict__ xtcat, int off_out,
                                                   float* __restrict__ xT, float* __restrict__ sqn,
                                                   __hip_bfloat16* __restrict__ xbf) {
    __shared__ float tile[64][O + 1];
    __shared__ float ssh[O], tth[O];
    int n0 = blockIdx.x * 64;
    int b = n0 >> 10;
    int tid = threadIdx.x;
    for (int o = tid; o < O; o += 256) {
        double sd = 0.0, qd = 0.0;
        for (int r = 0; r < 32; r++) { sd += r1s[(size_t)r * O + o]; qd += r1q[(size_t)r * O + o]; }
        double mean = sd * invM;
        double var = qd * invM - mean * mean;
        float inv = (float)(1.0 / sqrt(var + 1e-5));
        float sc = g[o] * inv;
        ssh[o] = sc;
        tth[o] = beta[o] - (float)mean * sc;
    }
    __syncthreads();
    for (int i = tid; i < 64 * O; i += 256) {
        int nl = i / O;
        int o = i & (O - 1);
        int n = n0 + nl;
        float sc = ssh[o];
        float v = sc >= 0.f ? ymax[(size_t)n * O + o] : ymin[(size_t)n * O + o];
        float y = sc * v + tth[o];
        y = y >= 0.f ? y : 0.2f * y;
        xtcat[(size_t)n * LDC + off_out + o] = y;
        xbf[(size_t)n * LDC + off_out + o] = __float2bfloat16(y);
        tile[nl][o] = y;
    }
    __syncthreads();
    if (tid < 64) {
        float sq = 0.f;
        for (int c = 0; c < O; c++) { float v = tile[tid][c]; sq += v * v; }
        sqn[n0 + tid] = sq;
    }
    int r = tid >> 4, cq = tid & 15;
#pragma unroll
    for (int ct = 0; ct < O / 16; ct++) {
        int c = ct * 16 + r;
        float4 ov;
        ov.x = tile[4 * cq + 0][c];
        ov.y = tile[4 * cq + 1][c];
        ov.z = tile[4 * cq + 2][c];
        ov.w = tile[4 * cq + 3][c];
        *(float4*)(xT + ((size_t)b * O + c) * 1024 + (n0 & (NN - 1)) + 4 * cq) = ov;
    }
}

// ---------------- stage-4 epilogue: s/t in-block, writes xbf ONLY (256 blocks x 32 rows) ----------------
__global__ __launch_bounds__(256) void epilogue4_k(const float* __restrict__ ymax, const float* __restrict__ ymin,
                                                   const float* __restrict__ r1s, const float* __restrict__ r1q,
                                                   const float* __restrict__ g, const float* __restrict__ beta,
                                                   double invM,
                                                   __hip_bfloat16* __restrict__ xbf) {
    __shared__ float ssh[256], tth[256];
    int n0 = blockIdx.x * 32;
    int tid = threadIdx.x;
    {
        int o = tid;
        double sd = 0.0, qd = 0.0;
        for (int r = 0; r < 32; r++) { sd += r1s[(size_t)r * 256 + o]; qd += r1q[(size_t)r * 256 + o]; }
        double mean = sd * invM;
        double var = qd * invM - mean * mean;
        float inv = (float)(1.0 / sqrt(var + 1e-5));
        float sc = g[o] * inv;
        ssh[o] = sc;
        tth[o] = beta[o] - (float)mean * sc;
    }
    __syncthreads();
    for (int i = tid; i < 32 * 256; i += 256) {
        int nl = i >> 8;
        int o = i & 255;
        int n = n0 + nl;
        float sc = ssh[o];
        float v = sc >= 0.f ? ymax[(size_t)n * 256 + o] : ymin[(size_t)n * 256 + o];
        float y = sc * v + tth[o];
        y = y >= 0.f ? y : 0.2f * y;
        xbf[(size_t)n * LDC + 256 + o] = __float2bfloat16(y);
    }
}

// ---------------- stage 5: bf16 MFMA GEMM (W staged from fp32 w5) w/ fused stats ----------------
__global__ __launch_bounds__(256) void gemm5_mfma(const __hip_bfloat16* __restrict__ xbf,
                                                  const float* __restrict__ w5,
                                                  float* __restrict__ pmax, float* __restrict__ pmn,
                                                  float* __restrict__ ps, float* __restrict__ pq) {
    __shared__ __hip_bfloat16 A[128][72];
    __shared__ __hip_bfloat16 W[128][72];
    int mt = blockIdx.x >> 2, nt = blockIdx.x & 3;
    int tid = threadIdx.x;
    int lane = tid & 63, wvx = tid >> 6;
    int mw = wvx >> 1, nw = wvx & 1;
    int m0 = lane & 15, qd = lane >> 4;
    int r = tid & 127, hf = tid >> 7;
    facc4 acc[4][4];
    facc4 zz = {0.f, 0.f, 0.f, 0.f};
#pragma unroll
    for (int mi = 0; mi < 4; mi++)
#pragma unroll
        for (int ni = 0; ni < 4; ni++) acc[mi][ni] = zz;
    for (int kc = 0; kc < 8; kc++) {
        const __hip_bfloat16* ap = xbf + (size_t)(mt * 128 + r) * 512 + kc * 64 + hf * 32;
        const float* wp = w5 + (size_t)(nt * 128 + r) * 512 + kc * 64 + hf * 32;
#pragma unroll
        for (int u = 0; u < 4; u++) {
            bh8 av = *(const bh8*)(ap + 8 * u);
            *(bh8*)&A[r][hf * 32 + 8 * u] = av;
            float4 w0 = *(const float4*)(wp + 8 * u);
            float4 w1 = *(const float4*)(wp + 8 * u + 4);
            *(bh8*)&W[r][hf * 32 + 8 * u] = cvt8(w0, w1);
        }
        __syncthreads();
#pragma unroll
        for (int kk = 0; kk < 2; kk++) {
            bfrag8 af[4], bf[4];
#pragma unroll
            for (int mi = 0; mi < 4; mi++)
                af[mi] = *(const bfrag8*)&A[64 * mw + 16 * mi + m0][32 * kk + 8 * qd];
#pragma unroll
            for (int ni = 0; ni < 4; ni++)
                bf[ni] = *(const bfrag8*)&W[64 * nw + 16 * ni + m0][32 * kk + 8 * qd];
#pragma unroll
            for (int mi = 0; mi < 4; mi++)
#pragma unroll
                for (int ni = 0; ni < 4; ni++)
                    acc[mi][ni] = __builtin_amdgcn_mfma_f32_16x16x32_bf16(af[mi], bf[ni], acc[mi][ni], 0, 0, 0);
        }
        __syncthreads();
    }
#pragma unroll
    for (int mi = 0; mi < 4; mi++) {
        int grp = mt * 8 + mw * 4 + mi;
#pragma unroll
        for (int ni = 0; ni < 4; ni++) {
            float mx = -INFINITY, mn = INFINITY, s = 0.f, ss = 0.f;
#pragma unroll
            for (int rg = 0; rg < 4; rg++) {
                float v = acc[mi][ni][rg];
                mx = fmaxf(mx, v); mn = fminf(mn, v); s += v; ss += v * v;
            }
#pragma unroll
            for (int m = 16; m < 64; m <<= 1) {
                mx = fmaxf(mx, __shfl_xor(mx, m));
                mn = fminf(mn, __shfl_xor(mn, m));
                s += __shfl_xor(s, m);
                ss += __shfl_xor(ss, m);
            }
            if (qd == 0) {
                int o = nt * 128 + nw * 64 + ni * 16 + m0;
                pmax[(size_t)grp * 512 + o] = mx;
                pmn [(size_t)grp * 512 + o] = mn;
                ps  [(size_t)grp * 512 + o] = s;
                pq  [(size_t)grp * 512 + o] = ss;
            }
        }
    }
}

// ---------------- stage-5 BN stats: 64 blocks x 8 channels ----------------
__global__ __launch_bounds__(256) void bnstat5_k(const float* __restrict__ ps, const float* __restrict__ pq,
                                                 const float* __restrict__ g, const float* __restrict__ beta,
                                                 float* __restrict__ s_out, float* __restrict__ t_out) {
    __shared__ double lds_s[4][8], lds_q[4][8];
    int tid = threadIdx.x;
    int lane = tid & 63, wv = tid >> 6;
    int ol = lane & 7;
    int rg = wv * 8 + (lane >> 3);
    int o = blockIdx.x * 8 + ol;
    double s = 0.0, q = 0.0;
    for (int r = rg; r < 512; r += 32) {
        s += ps[(size_t)r * 512 + o];
        q += pq[(size_t)r * 512 + o];
    }
    s += __shfl_xor(s, 8);  q += __shfl_xor(q, 8);
    s += __shfl_xor(s, 16); q += __shfl_xor(q, 16);
    s += __shfl_xor(s, 32); q += __shfl_xor(q, 32);
    if (lane < 8) { lds_s[wv][ol] = s; lds_q[wv][ol] = q; }
    __syncthreads();
    if (tid < 8) {
        s = lds_s[0][tid] + lds_s[1][tid] + lds_s[2][tid] + lds_s[3][tid];
        q = lds_q[0][tid] + lds_q[1][tid] + lds_q[2][tid] + lds_q[3][tid];
        double invM = 1.0 / (BB * NN);
        double mean = s * invM;
        double var = q * invM - mean * mean;
        float inv = (float)(1.0 / sqrt(var + 1e-5));
        int oo = blockIdx.x * 8 + tid;
        float sc = g[oo] * inv;
        s_out[oo] = sc;
        t_out[oo] = beta[oo] - (float)mean * sc;
    }
}

// ---------------- per-batch max/min reduce + BN + lrelu -> feat8 (64 blocks) ----------------
__global__ __launch_bounds__(256) void featreduce_k(const float* __restrict__ pmax, const float* __restrict__ pmn,
                                                    const float* __restrict__ s, const float* __restrict__ t,
                                                    float* __restrict__ feat8) {
    __shared__ float smx[4][64], smn[4][64];
    int blk = blockIdx.x;
    int b = blk >> 3, oc = blk & 7;
    int tid = threadIdx.x;
    int lane = tid & 63, wv = tid >> 6;
    int o = oc * 64 + lane;
    float mx = -INFINITY, mn = INFINITY;
    for (int r = b * 64 + wv; r < (b + 1) * 64; r += 4) {
        mx = fmaxf(mx, pmax[(size_t)r * 512 + o]);
        mn = fminf(mn, pmn [(size_t)r * 512 + o]);
    }
    smx[wv][lane] = mx; smn[wv][lane] = mn;
    __syncthreads();
    if (wv == 0) {
        mx = fmaxf(fmaxf(smx[0][lane], smx[1][lane]), fmaxf(smx[2][lane], smx[3][lane]));
        mn = fminf(fminf(smn[0][lane], smn[1][lane]), fminf(smn[2][lane], smn[3][lane]));
        float sc = s[o];
        float v = sc >= 0.f ? mx : mn;
        float y = sc * v + t[o];
        feat8[(size_t)b * 512 + o] = y >= 0.f ? y : 0.2f * y;
    }
}

// ---------------- final gemm: out[8][256] = feat8 @ wemb^T (64 blocks, split-K) ----------------
__global__ __launch_bounds__(256) void outgemm_k(const float* __restrict__ feat8,
                                                 const float* __restrict__ wemb,
                                                 float* __restrict__ out) {
    __shared__ __align__(16) float feat[512];
    int blk = blockIdx.x;
    int b = blk >> 3, nc = blk & 7;
    int tid = threadIdx.x;
    for (int i = tid; i < 512; i += 256) feat[i] = feat8[(size_t)b * 512 + i];
    __syncthreads();
    int o_l = tid >> 3, kc = tid & 7;
    int o = nc * 32 + o_l;
    const float4* wr = (const float4*)(wemb + (size_t)o * 512 + kc * 64);
    const float4* fv = (const float4*)(feat + kc * 64);
    float acc = 0.f;
#pragma unroll
    for (int i = 0; i < 16; i++) {
        float4 wv = wr[i];
        float4 f  = fv[i];
        acc += wv.x * f.x + wv.y * f.y + wv.z * f.z + wv.w * f.w;
    }
    acc += __shfl_xor(acc, 1);
    acc += __shfl_xor(acc, 2);
    acc += __shfl_xor(acc, 4);
    if (kc == 0) out[(size_t)b * 256 + o] = acc;
}

extern "C" void kernel_launch(void* const* d_in, const int* in_sizes, int n_in,
                              void* d_out, int out_size, void* d_ws, size_t ws_size,
                              hipStream_t stream) {
    const float* x    = (const float*)d_in[0];
    const float* w1   = (const float*)d_in[1];
    const float* g1   = (const float*)d_in[2];
    const float* b1   = (const float*)d_in[3];
    const float* w2   = (const float*)d_in[4];
    const float* g2   = (const float*)d_in[5];
    const float* b2   = (const float*)d_in[6];
    const float* w3   = (const float*)d_in[7];
    const float* g3   = (const float*)d_in[8];
    const float* b3   = (const float*)d_in[9];
    const float* w4   = (const float*)d_in[10];
    const float* g4   = (const float*)d_in[11];
    const float* b4   = (const float*)d_in[12];
    const float* w5   = (const float*)d_in[13];
    const float* g5   = (const float*)d_in[14];
    const float* b5   = (const float*)d_in[15];
    const float* wemb = (const float*)d_in[16];
    float* out = (float*)d_out;

    float* fws    = (float*)d_ws;
    float* xtcat  = fws;                                 // 4,194,304
    float* ymax   = xtcat + (size_t)BB * NN * 512;       // 2,097,152
    float* ymin   = ymax + (size_t)BB * NN * 256;        // 2,097,152
    float* psum   = ymin + (size_t)BB * NN * 256;        // 2,097,152 (xT alias)
    float* psumsq = psum + (size_t)BB * NN * 256;        // 2,097,152 (spare; feat8 lives here at stage 5)
    float* xT     = psum;                                // alias
    float* pmax   = ymax;                                // alias: stage-5 partials
    float* pmn    = pmax + 512 * 512;
    float* ps5    = pmn + 512 * 512;
    float* pq5    = ps5 + 512 * 512;
    float* feat8  = psumsq;                              // 8*512 floats (stage-5 features)
    float* sqn    = psumsq + (size_t)BB * NN * 256;      // 8192
    float* s_arr  = sqn + BB * NN;                       // 512
    float* t_arr  = s_arr + 512;                         // 512
    float* r1s    = t_arr + 512;                         // 32*512
    float* r1q    = r1s + 32 * 512;                      // 32*512
    int*   idxb   = (int*)(r1q + 32 * 512);              // 8192*20 ints
    float* zfull  = (float*)(idxb + BB * NN * KNNK);     // 8192*512 fp32 (stages 1-3)
    __hip_bfloat16* zf4 = (__hip_bfloat16*)zfull;        // alias: stage-4 z, bf16
    __hip_bfloat16* xbf = (__hip_bfloat16*)(zfull + (size_t)BB * NN * 512);   // 8192*512 bf16

    const double invM_edge = 1.0 / ((double)BB * NN * KNNK);
    const int nbn = BB * NN;
    const int NK  = nbn / 8;      // 1024 knn blocks (stage 1, 8 q/block)
    const int NK16 = nbn / 16;    // 512 knn blocks (stages 2-4, 16 q/block)
    const int NZ  = nbn / 16;     // 512 zgemm blocks

    // ---- Stage 1 ----
    knn3_fused<<<NK, 256, 0, stream>>>(x, w1, zfull, idxb, r1s, r1q);
    gatherstats_k<128><<<nbn / 4, 256, 0, stream>>>(zfull, idxb, ymax, ymin, r1s, r1q);
    epitrans2_k<64><<<128, 256, 0, stream>>>(ymax, ymin, r1s, r1q, g1, b1, invM_edge, xtcat, 0, xT, sqn, xbf);

    // ---- Stage 2 ----
    knnz_fat<64, 128><<<NK16 + NZ, 256, 0, stream>>>(xT, xtcat, 0, sqn, idxb, w2, zfull, r1s, r1q, 64);
    gatherstats_k<128><<<nbn / 4, 256, 0, stream>>>(zfull, idxb, ymax, ymin, r1s, r1q);
    epitrans2_k<64><<<128, 256, 0, stream>>>(ymax, ymin, r1s, r1q, g2, b2, invM_edge, xtcat, 64, xT, sqn, xbf);

    // ---- Stage 3 ----
    knnz_fat<64, 256><<<NK16 + NZ, 256, 0, stream>>>(xT, xtcat, 64, sqn, idxb, w3, zfull, r1s, r1q, 128);
    gatherstats_k<256><<<nbn / 4, 256, 0, stream>>>(zfull, idxb, ymax, ymin, r1s, r1q);
    epitrans2_k<128><<<128, 256, 0, stream>>>(ymax, ymin, r1s, r1q, g3, b3, invM_edge, xtcat, 128, xT, sqn, xbf);

    // ---- Stage 4 (knn 16q || zgemm4 in one fat launch) ----
    knnz4_fat<<<NK16 + 256, 256, 0, stream>>>(xT, sqn, idxb, xtcat, w4, zf4, r1s, r1q);
    gatherstats4_k<<<nbn / 4, 256, 0, stream>>>(zf4, idxb, ymax, ymin, r1s, r1q);
    epilogue4_k<<<256, 256, 0, stream>>>(ymax, ymin, r1s, r1q, g4, b4, invM_edge, xbf);

    // ---- Stage 5 ----
    gemm5_mfma<<<256, 256, 0, stream>>>(xbf, w5, pmax, pmn, ps5, pq5);
    bnstat5_k<<<64, 256, 0, stream>>>(ps5, pq5, g5, b5, s_arr, t_arr);
    featreduce_k<<<64, 256, 0, stream>>>(pmax, pmn, s_arr, t_arr, feat8);
    outgemm_k<<<64, 256, 0, stream>>>(feat8, wemb, out);
}

// Round 12
// 330.630 us; speedup vs baseline: 1.4411x; 1.4411x over previous
//
#include <hip/hip_runtime.h>
#include <hip/hip_bf16.h>
#include <math.h>

#define BB 8
#define NN 1024
#define KNNK 20
#define LDC 512

typedef __attribute__((ext_vector_type(8))) short bfrag8;
typedef __attribute__((ext_vector_type(4))) float facc4;
typedef __attribute__((ext_vector_type(2))) float v2f;

struct bh8 { __hip_bfloat16 h[8]; };

__device__ __forceinline__ bh8 cvt8(float4 a, float4 b) {
    bh8 v;
    v.h[0] = __float2bfloat16(a.x); v.h[1] = __float2bfloat16(a.y);
    v.h[2] = __float2bfloat16(a.z); v.h[3] = __float2bfloat16(a.w);
    v.h[4] = __float2bfloat16(b.x); v.h[5] = __float2bfloat16(b.y);
    v.h[6] = __float2bfloat16(b.z); v.h[7] = __float2bfloat16(b.w);
    return v;
}

// ---- DPP wave64 max reduce: 6 VALU-pipe steps, no ds_bpermute on the chain ----
template<int CTRL, int RMASK>
__device__ __forceinline__ float fmax_dpp(float x) {
    int xi = __float_as_int(x);
    int yi = __builtin_amdgcn_update_dpp(xi, xi, CTRL, RMASK, 0xF, false);
    return fmaxf(x, __int_as_float(yi));
}

__device__ __forceinline__ float wave_max64(float x) {
    x = fmax_dpp<0x121, 0xF>(x);   // row_ror:1
    x = fmax_dpp<0x122, 0xF>(x);   // row_ror:2
    x = fmax_dpp<0x124, 0xF>(x);   // row_ror:4
    x = fmax_dpp<0x128, 0xF>(x);   // row_ror:8  -> each lane = max of its row(16)
    x = fmax_dpp<0x142, 0xA>(x);   // row_bcast15 -> rows 1,3 combine with rows 0,2
    x = fmax_dpp<0x143, 0xC>(x);   // row_bcast31 -> lane63 = wave max
    return __int_as_float(__builtin_amdgcn_readlane(__float_as_int(x), 63));
}

// ---------------- top-20 selection: per-lane Batcher sort (regs) -> LDS write-back,
// merge with DPP wave-max + register head/prefetch (2 queries/wave, interleaved ILP) ----------------
__device__ __forceinline__ void select20_pf(float (*dist)[1024],
                                            int q0, int w, int lane,
                                            int* __restrict__ idxout) {
    float d[2][16];
    int   sl[2][16];
#pragma unroll
    for (int qi = 0; qi < 2; qi++) {
        int row = w * 2 + qi;
#pragma unroll
        for (int j = 0; j < 16; j++) { d[qi][j] = dist[row][lane + 64 * j]; sl[qi][j] = j; }
    }
    constexpr unsigned char CA[63] = {
        0,2,4,6,8,10,12,14,
        0,1,4,5,8,9,12,13,
        1,5,9,13,
        0,1,2,3,8,9,10,11,
        2,3,10,11,
        1,3,5,9,11,13,
        0,1,2,3,4,5,6,7,
        4,5,6,7,
        2,3,6,7,10,11,
        1,3,5,7,9,11,13};
    constexpr unsigned char CB[63] = {
        1,3,5,7,9,11,13,15,
        2,3,6,7,10,11,14,15,
        2,6,10,14,
        4,5,6,7,12,13,14,15,
        4,5,12,13,
        2,4,6,10,12,14,
        8,9,10,11,12,13,14,15,
        8,9,10,11,
        4,5,8,9,12,13,
        2,4,6,8,10,12,14};
#pragma unroll
    for (int c = 0; c < 63; c++) {
        const int a = CA[c], bq = CB[c];
#pragma unroll
        for (int qi = 0; qi < 2; qi++) {
            bool sw = d[qi][a] < d[qi][bq];
            float dmx = sw ? d[qi][bq] : d[qi][a];
            float dmn = sw ? d[qi][a]  : d[qi][bq];
            d[qi][a] = dmx; d[qi][bq] = dmn;
            int smx = sw ? sl[qi][bq] : sl[qi][a];
            int smn = sw ? sl[qi][a]  : sl[qi][bq];
            sl[qi][a] = smx; sl[qi][bq] = smn;
        }
    }
    // write sorted values back to LDS (backing store for deep refills) and pack the
    // slot queue into one u64 per query (4 bits/slot).
    unsigned long long slp[2];
#pragma unroll
    for (int qi = 0; qi < 2; qi++) {
        int row = w * 2 + qi;
#pragma unroll
        for (int j = 0; j < 16; j++) dist[row][j * 64 + lane] = d[qi][j];
        unsigned long long p = 0;
#pragma unroll
        for (int j = 0; j < 16; j++) p |= (unsigned long long)sl[qi][j] << (4 * j);
        slp[qi] = p;
    }
    // merge state: head + one prefetched value per query; refill loads issued by the
    // winner right after consumption -> latency hidden behind the next round's reduce.
    float head[2] = {d[0][0], d[1][0]};
    float pf[2]   = {d[0][1], d[1][1]};
    int   ptr[2]  = {2, 2};
    for (int t = 0; t < KNNK; t++) {
#pragma unroll
        for (int qi = 0; qi < 2; qi++) {
            int row = w * 2 + qi;
            float bv = wave_max64(head[qi]);
            unsigned long long ball = __ballot(head[qi] == bv);
            int wl = (int)__builtin_ctzll(ball);
            bool win = (lane == wl);
            if (win) {
                idxout[(q0 + row) * KNNK + t] = (int)(slp[qi] & 15ull) * 64 + lane;
            }
            head[qi] = win ? pf[qi] : head[qi];
            slp[qi]  = win ? (slp[qi] >> 4) : slp[qi];
            if (win) {
                int p = ptr[qi];
                pf[qi] = (p < 16) ? dist[row][p * 64 + lane] : -INFINITY;
                ptr[qi] = p + 1;
            }
        }
    }
}

// r1 zeroing helper (done by one designated block of the kernel preceding the gather)
__device__ __forceinline__ void zero_r1(float* r1s, float* r1q, int O, int tid) {
    for (int i = tid; i < 32 * O; i += 256) { r1s[i] = 0.f; r1q[i] = 0.f; }
}

// ---------------- fused kNN stage 1 (C=3) + stage-1 z-gemm, 8 queries/block ----------------
__global__ __launch_bounds__(256, 4) void knn3_fused(const float* __restrict__ x,
                                                     const float* __restrict__ w1,
                                                     float* __restrict__ zf,
                                                     int* __restrict__ idxout,
                                                     float* __restrict__ r1s, float* __restrict__ r1q) {
    __shared__ float dist[8][1024];
    int tid = threadIdx.x;
    int q0 = (blockIdx.x & 7) * 1024 + (blockIdx.x >> 3) * 8;   // XCD swizzle
    int b = q0 >> 10;
    if (blockIdx.x == 0) zero_r1(r1s, r1q, 64, tid);
    const float* xb = x + (size_t)b * NN * 3;
    int lane = tid & 63, w = tid >> 6;
    float qx[8], qy[8], qz[8];
#pragma unroll
    for (int q = 0; q < 8; q++) {
        const float* qr = xb + (size_t)((q0 & (NN - 1)) + q) * 3;
        qx[q] = qr[0]; qy[q] = qr[1]; qz[q] = qr[2];
    }
#pragma unroll
    for (int cq = 0; cq < 4; cq++) {
        int cand = w * 256 + cq * 64 + lane;
        const float* cr = xb + (size_t)cand * 3;
        float cx = cr[0], cy = cr[1], cz = cr[2];
        float sqc = cx * cx + cy * cy + cz * cz;
#pragma unroll
        for (int q = 0; q < 8; q++) {
            float d = qx[q] * cx + qy[q] * cy + qz[q] * cz;
            dist[q][cand] = 2.f * d - sqc;
        }
    }
    for (int i = tid; i < 8 * 128; i += 256) {
        int lq = i >> 7, j = i & 127;
        const float* wr = w1 + (j < 64 ? j * 6 : (j - 64) * 6 + 3);
        const float* xr = x + (size_t)(q0 + lq) * 3;
        zf[(size_t)(q0 + lq) * 128 + j] = wr[0] * xr[0] + wr[1] * xr[1] + wr[2] * xr[2];
    }
    __syncthreads();
    select20_pf(dist, q0, w, lane, idxout);
}

// ---------------- knn core (stages 2-4): 8 queries/block, queries via wave-uniform loads ----------------
template<int C>
__device__ __forceinline__ void knn_body(const float* __restrict__ xT,
                                         const float* __restrict__ sqn,
                                         int* __restrict__ idxout,
                                         float (*dist)[1024], int knnBlk) {
    int tid = threadIdx.x;
    int q0 = (knnBlk & 7) * 1024 + (knnBlk >> 3) * 8;           // XCD swizzle
    int b = q0 >> 10;
    int lane = tid & 63, w = tid >> 6;
    int cand0 = w * 256 + 4 * lane;
    const float* xTb = xT + (size_t)b * C * 1024;
    const float* qrow = xTb + (q0 & (NN - 1));                  // block-uniform base
    float4 sq4 = *(const float4*)(sqn + b * NN + cand0);
    v2f acc2[4][4];
#pragma unroll
    for (int j = 0; j < 4; j++)
#pragma unroll
        for (int p = 0; p < 4; p++) acc2[j][p] = (v2f){0.f, 0.f};
    for (int cg = 0; cg < C / 4; cg++) {
        float4 rch[4];
#pragma unroll
        for (int c = 0; c < 4; c++)
            rch[c] = *(const float4*)(xTb + (size_t)(4 * cg + c) * 1024 + cand0);
#pragma unroll
        for (int c = 0; c < 4; c++) {
            const float* qr = qrow + (size_t)(4 * cg + c) * 1024;
            float4 qa = *(const float4*)qr;                     // uniform -> s_load
            float4 qb = *(const float4*)(qr + 4);
            v2f qp[4] = {{qa.x, qa.y}, {qa.z, qa.w}, {qb.x, qb.y}, {qb.z, qb.w}};
            float rj[4] = {rch[c].x, rch[c].y, rch[c].z, rch[c].w};
#pragma unroll
            for (int j = 0; j < 4; j++) {
                v2f rr = {rj[j], rj[j]};
                acc2[j][0] += rr * qp[0];
                acc2[j][1] += rr * qp[1];
                acc2[j][2] += rr * qp[2];
                acc2[j][3] += rr * qp[3];
            }
        }
    }
#pragma unroll
    for (int p = 0; p < 4; p++)
#pragma unroll
        for (int half = 0; half < 2; half++) {
            int q = 2 * p + half;
            float4 dv;
            dv.x = 2.f * acc2[0][p][half] - sq4.x;
            dv.y = 2.f * acc2[1][p][half] - sq4.y;
            dv.z = 2.f * acc2[2][p][half] - sq4.z;
            dv.w = 2.f * acc2[3][p][half] - sq4.w;
            *(float4*)&dist[q][cand0] = dv;
        }
    __syncthreads();
    select20_pf(dist, q0, w, lane, idxout);
}

// ---------------- FAT kernel stages 2-3: knn (blocks<1024) + zgemm (blocks>=1024) ----------------
template<int C, int ZO2>
__global__ __launch_bounds__(256, 4) void knnz_fat(const float* __restrict__ xT,
                                                   const float* __restrict__ xt, int off,
                                                   const float* __restrict__ sqn,
                                                   int* __restrict__ idxout,
                                                   const float* __restrict__ w,
                                                   float* __restrict__ zf,
                                                   float* __restrict__ r1s, float* __restrict__ r1q,
                                                   int Onext) {
    __shared__ float dist[8][1024];
    int tid = threadIdx.x;
    if ((int)blockIdx.x < BB * NN / 8) {
        knn_body<C>(xT, sqn, idxout, dist, blockIdx.x);
        return;
    }
    // ---- zgemm path ----
    constexpr int ZO = ZO2 / 2;
    int zblk = blockIdx.x - BB * NN / 8;
    if (zblk == 0) zero_r1(r1s, r1q, Onext, tid);
    float (*xs)[C] = (float (*)[C])&dist[0][0];
    int p0 = zblk * 16;
    for (int j = tid; j < 16 * (C / 4); j += 256) {
        int p = j / (C / 4), c4 = j % (C / 4);
        *(float4*)&xs[p][4 * c4] = *(const float4*)(xt + (size_t)(p0 + p) * LDC + off + 4 * c4);
    }
    __syncthreads();
    for (int j = tid; j < ZO2; j += 256) {
        const float* wr = w + (j < ZO ? (size_t)j * 2 * C : (size_t)(j - ZO) * 2 * C + C);
        float acc[16];
#pragma unroll
        for (int p = 0; p < 16; p++) acc[p] = 0.f;
        for (int c4 = 0; c4 < C / 4; c4++) {
            float4 wv = *(const float4*)(wr + 4 * c4);
#pragma unroll
            for (int p = 0; p < 16; p++) {
                float4 xv = *(const float4*)&xs[p][4 * c4];
                acc[p] += wv.x * xv.x + wv.y * xv.y + wv.z * xv.z + wv.w * xv.w;
            }
        }
#pragma unroll
        for (int p = 0; p < 16; p++) zf[(size_t)(p0 + p) * ZO2 + j] = acc[p];
    }
}

// ---------------- FAT stage 4: knn<128> (blocks<1024) + bf16 MFMA zgemm (blocks>=1024) ----------------
__global__ __launch_bounds__(256, 4) void knnz4_fat(const float* __restrict__ xT,
                                                    const float* __restrict__ sqn,
                                                    int* __restrict__ idxout,
                                                    const float* __restrict__ xtcat,
                                                    const float* __restrict__ w4,
                                                    __hip_bfloat16* __restrict__ zf4,
                                                    float* __restrict__ r1s, float* __restrict__ r1q) {
    __shared__ __align__(16) char smem[36864];
    int tid = threadIdx.x;
    if ((int)blockIdx.x < BB * NN / 8) {
        float (*dist)[1024] = (float (*)[1024])smem;
        if (blockIdx.x == 0) zero_r1(r1s, r1q, 256, tid);
        knn_body<128>(xT, sqn, idxout, dist, blockIdx.x);
        return;
    }
    // ---- zgemm4 path (bf16 MFMA) ----
    __hip_bfloat16 (*A)[72] = (__hip_bfloat16 (*)[72])smem;
    __hip_bfloat16 (*W)[72] = (__hip_bfloat16 (*)[72])(smem + 18432);
    int zblk = blockIdx.x - BB * NN / 8;
    int mt = zblk >> 2, nt = zblk & 3;
    int lane = tid & 63, wvx = tid >> 6;
    int mw = wvx >> 1, nw = wvx & 1;
    int m0 = lane & 15, qd = lane >> 4;
    int r = tid & 127, hf = tid >> 7;
    facc4 acc[4][4];
    facc4 zz = {0.f, 0.f, 0.f, 0.f};
#pragma unroll
    for (int mi = 0; mi < 4; mi++)
#pragma unroll
        for (int ni = 0; ni < 4; ni++) acc[mi][ni] = zz;
    int j = nt * 128 + r;
    const float* wsrc = w4 + (j < 256 ? (size_t)j * 256 : (size_t)(j - 256) * 256 + 128);
    const float* asrc = xtcat + (size_t)(mt * 128 + r) * 512 + 128;
    for (int kc = 0; kc < 2; kc++) {
#pragma unroll
        for (int u = 0; u < 4; u++) {
            int c0 = kc * 64 + hf * 32 + 8 * u;
            float4 a0 = *(const float4*)(asrc + c0);
            float4 a1 = *(const float4*)(asrc + c0 + 4);
            *(bh8*)&A[r][hf * 32 + 8 * u] = cvt8(a0, a1);
            float4 w0 = *(const float4*)(wsrc + c0);
            float4 w1 = *(const float4*)(wsrc + c0 + 4);
            *(bh8*)&W[r][hf * 32 + 8 * u] = cvt8(w0, w1);
        }
        __syncthreads();
#pragma unroll
        for (int kk = 0; kk < 2; kk++) {
            bfrag8 af[4], bf[4];
#pragma unroll
            for (int mi = 0; mi < 4; mi++)
                af[mi] = *(const bfrag8*)&A[64 * mw + 16 * mi + m0][32 * kk + 8 * qd];
#pragma unroll
            for (int ni = 0; ni < 4; ni++)
                bf[ni] = *(const bfrag8*)&W[64 * nw + 16 * ni + m0][32 * kk + 8 * qd];
#pragma unroll
            for (int mi = 0; mi < 4; mi++)
#pragma unroll
                for (int ni = 0; ni < 4; ni++)
                    acc[mi][ni] = __builtin_amdgcn_mfma_f32_16x16x32_bf16(af[mi], bf[ni], acc[mi][ni], 0, 0, 0);
        }
        __syncthreads();
    }
#pragma unroll
    for (int mi = 0; mi < 4; mi++)
#pragma unroll
        for (int ni = 0; ni < 4; ni++)
#pragma unroll
            for (int rg = 0; rg < 4; rg++) {
                int row = mt * 128 + mw * 64 + mi * 16 + qd * 4 + rg;
                int col = nt * 128 + nw * 64 + ni * 16 + m0;
                zf4[(size_t)row * 512 + col] = __float2bfloat16(acc[mi][ni][rg]);
            }
}

// ---------------- gather + stats (fp32 zf, stages 1-3): in-block reduce + atomics ----------------
template<int O2>
__global__ __launch_bounds__(256) void gatherstats_k(const float* __restrict__ zf,
                                                     const int* __restrict__ idx,
                                                     float* __restrict__ ymax, float* __restrict__ ymin,
                                                     float* __restrict__ r1s, float* __restrict__ r1q) {
    constexpr int O = O2 / 2;
    __shared__ float red_s[4][O], red_q[4][O];
    int wv = threadIdx.x >> 6, lane = threadIdx.x & 63;
    int n = (blockIdx.x & 7) * 1024 + (blockIdx.x >> 3) * 4 + wv;   // XCD swizzle
    int b = n >> 10;
    const float* zbatch = zf + (size_t)b * NN * O2;
    int nb[KNNK];
#pragma unroll
    for (int k = 0; k < KNNK; k++) nb[k] = idx[n * KNNK + k];
#pragma unroll
    for (int ch = 0; ch < O / 64; ch++) {
        int o = ch * 64 + lane;
        float g[KNNK];
#pragma unroll
        for (int k = 0; k < KNNK; k++) g[k] = zbatch[(size_t)nb[k] * O2 + o];
        float mx = -INFINITY, mn = INFINITY, s = 0.f, ss = 0.f;
#pragma unroll
        for (int k = 0; k < KNNK; k++) {
            float v = g[k];
            mx = fmaxf(mx, v); mn = fminf(mn, v); s += v; ss += v * v;
        }
        float zn  = zf[(size_t)n * O2 + o];
        float zbn = zf[(size_t)n * O2 + O + o];
        float d = zbn - zn;
        mx += d; mn += d;
        ss = ss + 2.f * d * s + (float)KNNK * d * d;
        s  = s + (float)KNNK * d;
        ymax[(size_t)n * O + o] = mx;
        ymin[(size_t)n * O + o] = mn;
        red_s[wv][o] = s;
        red_q[wv][o] = ss;
    }
    __syncthreads();
    int bucket = blockIdx.x & 31;
    for (int o = threadIdx.x; o < O; o += 256) {
        float s4 = red_s[0][o] + red_s[1][o] + red_s[2][o] + red_s[3][o];
        float q4 = red_q[0][o] + red_q[1][o] + red_q[2][o] + red_q[3][o];
        atomicAdd(&r1s[(size_t)bucket * O + o], s4);
        atomicAdd(&r1q[(size_t)bucket * O + o], q4);
    }
}

// ---------------- gather + stats, bf16 zf4 (stage 4) ----------------
__global__ __launch_bounds__(256) void gatherstats4_k(const __hip_bfloat16* __restrict__ zf4,
                                                      const int* __restrict__ idx,
                                                      float* __restrict__ ymax, float* __restrict__ ymin,
                                                      float* __restrict__ r1s, float* __restrict__ r1q) {
    __shared__ float red_s[4][256], red_q[4][256];
    int wv = threadIdx.x >> 6, lane = threadIdx.x & 63;
    int n = (blockIdx.x & 7) * 1024 + (blockIdx.x >> 3) * 4 + wv;
    int b = n >> 10;
    const __hip_bfloat16* zbatch = zf4 + (size_t)b * NN * 512;
    int nb[KNNK];
#pragma unroll
    for (int k = 0; k < KNNK; k++) nb[k] = idx[n * KNNK + k];
#pragma unroll
    for (int ch = 0; ch < 4; ch++) {
        int o = ch * 64 + lane;
        float g[KNNK];
#pragma unroll
        for (int k = 0; k < KNNK; k++) g[k] = __bfloat162float(zbatch[(size_t)nb[k] * 512 + o]);
        float mx = -INFINITY, mn = INFINITY, s = 0.f, ss = 0.f;
#pragma unroll
        for (int k = 0; k < KNNK; k++) {
            float v = g[k];
            mx = fmaxf(mx, v); mn = fminf(mn, v); s += v; ss += v * v;
        }
        float zn  = __bfloat162float(zf4[(size_t)n * 512 + o]);
        float zbn = __bfloat162float(zf4[(size_t)n * 512 + 256 + o]);
        float d = zbn - zn;
        mx += d; mn += d;
        ss = ss + 2.f * d * s + (float)KNNK * d * d;
        s  = s + (float)KNNK * d;
        ymax[(size_t)n * 256 + o] = mx;
        ymin[(size_t)n * 256 + o] = mn;
        red_s[wv][o] = s;
        red_q[wv][o] = ss;
    }
    __syncthreads();
    int bucket = blockIdx.x & 31;
    for (int o = threadIdx.x; o < 256; o += 256) {
        float s4 = red_s[0][o] + red_s[1][o] + red_s[2][o] + red_s[3][o];
        float q4 = red_q[0][o] + red_q[1][o] + red_q[2][o] + red_q[3][o];
        atomicAdd(&r1s[(size_t)bucket * 256 + o], s4);
        atomicAdd(&r1q[(size_t)bucket * 256 + o], q4);
    }
}

// ---------------- BN+lrelu epilogue + transpose + |c|^2 + bf16 copy, s/t computed in-block ----------------
template<int O>
__global__ __launch_bounds__(256) void epitrans2_k(const float* __restrict__ ymax, const float* __restrict__ ymin,
                                                   const float* __restrict__ r1s, const float* __restrict__ r1q,
                                                   const float* __restrict__ g, const float* __restrict__ beta,
                                                   double invM,
                                                   float* __restrict__ xtcat, int off_out,
                                                   float* __restrict__ xT, float* __restrict__ sqn,
                                                   __hip_bfloat16* __restrict__ xbf) {
    __shared__ float tile[64][O + 1];
    __shared__ float ssh[O], tth[O];
    int n0 = blockIdx.x * 64;
    int b = n0 >> 10;
    int tid = threadIdx.x;
    for (int o = tid; o < O; o += 256) {
        double sd = 0.0, qd = 0.0;
        for (int r = 0; r < 32; r++) { sd += r1s[(size_t)r * O + o]; qd += r1q[(size_t)r * O + o]; }
        double mean = sd * invM;
        double var = qd * invM - mean * mean;
        float inv = (float)(1.0 / sqrt(var + 1e-5));
        float sc = g[o] * inv;
        ssh[o] = sc;
        tth[o] = beta[o] - (float)mean * sc;
    }
    __syncthreads();
    for (int i = tid; i < 64 * O; i += 256) {
        int nl = i / O;
        int o = i & (O - 1);
        int n = n0 + nl;
        float sc = ssh[o];
        float v = sc >= 0.f ? ymax[(size_t)n * O + o] : ymin[(size_t)n * O + o];
        float y = sc * v + tth[o];
        y = y >= 0.f ? y : 0.2f * y;
        xtcat[(size_t)n * LDC + off_out + o] = y;
        xbf[(size_t)n * LDC + off_out + o] = __float2bfloat16(y);
        tile[nl][o] = y;
    }
    __syncthreads();
    if (tid < 64) {
        float sq = 0.f;
        for (int c = 0; c < O; c++) { float v = tile[tid][c]; sq += v * v; }
        sqn[n0 + tid] = sq;
    }
    int r = tid >> 4, cq = tid & 15;
#pragma unroll
    for (int ct = 0; ct < O / 16; ct++) {
        int c = ct * 16 + r;
        float4 ov;
        ov.x = tile[4 * cq + 0][c];
        ov.y = tile[4 * cq + 1][c];
        ov.z = tile[4 * cq + 2][c];
        ov.w = tile[4 * cq + 3][c];
        *(float4*)(xT + ((size_t)b * O + c) * 1024 + (n0 & (NN - 1)) + 4 * cq) = ov;
    }
}

// ---------------- stage-4 epilogue: s/t in-block, writes xbf ONLY (256 blocks x 32 rows) ----------------
__global__ __launch_bounds__(256) void epilogue4_k(const float* __restrict__ ymax, const float* __restrict__ ymin,
                                                   const float* __restrict__ r1s, const float* __restrict__ r1q,
                                                   const float* __restrict__ g, const float* __restrict__ beta,
                                                   double invM,
                                                   __hip_bfloat16* __restrict__ xbf) {
    __shared__ float ssh[256], tth[256];
    int n0 = blockIdx.x * 32;
    int tid = threadIdx.x;
    {
        int o = tid;
        double sd = 0.0, qd = 0.0;
        for (int r = 0; r < 32; r++) { sd += r1s[(size_t)r * 256 + o]; qd += r1q[(size_t)r * 256 + o]; }
        double mean = sd * invM;
        double var = qd * invM - mean * mean;
        float inv = (float)(1.0 / sqrt(var + 1e-5));
        float sc = g[o] * inv;
        ssh[o] = sc;
        tth[o] = beta[o] - (float)mean * sc;
    }
    __syncthreads();
    for (int i = tid; i < 32 * 256; i += 256) {
        int nl = i >> 8;
        int o = i & 255;
        int n = n0 + nl;
        float sc = ssh[o];
        float v = sc >= 0.f ? ymax[(size_t)n * 256 + o] : ymin[(size_t)n * 256 + o];
        float y = sc * v + tth[o];
        y = y >= 0.f ? y : 0.2f * y;
        xbf[(size_t)n * LDC + 256 + o] = __float2bfloat16(y);
    }
}

// ---------------- stage 5: bf16 MFMA GEMM (W staged from fp32 w5) w/ fused stats ----------------
__global__ __launch_bounds__(256) void gemm5_mfma(const __hip_bfloat16* __restrict__ xbf,
                                                  const float* __restrict__ w5,
                                                  float* __restrict__ pmax, float* __restrict__ pmn,
                                                  float* __restrict__ ps, float* __restrict__ pq) {
    __shared__ __hip_bfloat16 A[128][72];
    __shared__ __hip_bfloat16 W[128][72];
    int mt = blockIdx.x >> 2, nt = blockIdx.x & 3;
    int tid = threadIdx.x;
    int lane = tid & 63, wvx = tid >> 6;
    int mw = wvx >> 1, nw = wvx & 1;
    int m0 = lane & 15, qd = lane >> 4;
    int r = tid & 127, hf = tid >> 7;
    facc4 acc[4][4];
    facc4 zz = {0.f, 0.f, 0.f, 0.f};
#pragma unroll
    for (int mi = 0; mi < 4; mi++)
#pragma unroll
        for (int ni = 0; ni < 4; ni++) acc[mi][ni] = zz;
    for (int kc = 0; kc < 8; kc++) {
        const __hip_bfloat16* ap = xbf + (size_t)(mt * 128 + r) * 512 + kc * 64 + hf * 32;
        const float* wp = w5 + (size_t)(nt * 128 + r) * 512 + kc * 64 + hf * 32;
#pragma unroll
        for (int u = 0; u < 4; u++) {
            bh8 av = *(const bh8*)(ap + 8 * u);
            *(bh8*)&A[r][hf * 32 + 8 * u] = av;
            float4 w0 = *(const float4*)(wp + 8 * u);
            float4 w1 = *(const float4*)(wp + 8 * u + 4);
            *(bh8*)&W[r][hf * 32 + 8 * u] = cvt8(w0, w1);
        }
        __syncthreads();
#pragma unroll
        for (int kk = 0; kk < 2; kk++) {
            bfrag8 af[4], bf[4];
#pragma unroll
            for (int mi = 0; mi < 4; mi++)
                af[mi] = *(const bfrag8*)&A[64 * mw + 16 * mi + m0][32 * kk + 8 * qd];
#pragma unroll
            for (int ni = 0; ni < 4; ni++)
                bf[ni] = *(const bfrag8*)&W[64 * nw + 16 * ni + m0][32 * kk + 8 * qd];
#pragma unroll
            for (int mi = 0; mi < 4; mi++)
#pragma unroll
                for (int ni = 0; ni < 4; ni++)
                    acc[mi][ni] = __builtin_amdgcn_mfma_f32_16x16x32_bf16(af[mi], bf[ni], acc[mi][ni], 0, 0, 0);
        }
        __syncthreads();
    }
#pragma unroll
    for (int mi = 0; mi < 4; mi++) {
        int grp = mt * 8 + mw * 4 + mi;
#pragma unroll
        for (int ni = 0; ni < 4; ni++) {
            float mx = -INFINITY, mn = INFINITY, s = 0.f, ss = 0.f;
#pragma unroll
            for (int rg = 0; rg < 4; rg++) {
                float v = acc[mi][ni][rg];
                mx = fmaxf(mx, v); mn = fminf(mn, v); s += v; ss += v * v;
            }
#pragma unroll
            for (int m = 16; m < 64; m <<= 1) {
                mx = fmaxf(mx, __shfl_xor(mx, m));
                mn = fminf(mn, __shfl_xor(mn, m));
                s += __shfl_xor(s, m);
                ss += __shfl_xor(ss, m);
            }
            if (qd == 0) {
                int o = nt * 128 + nw * 64 + ni * 16 + m0;
                pmax[(size_t)grp * 512 + o] = mx;
                pmn [(size_t)grp * 512 + o] = mn;
                ps  [(size_t)grp * 512 + o] = s;
                pq  [(size_t)grp * 512 + o] = ss;
            }
        }
    }
}

// ---------------- stage-5 BN stats: 64 blocks x 8 channels ----------------
__global__ __launch_bounds__(256) void bnstat5_k(const float* __restrict__ ps, const float* __restrict__ pq,
                                                 const float* __restrict__ g, const float* __restrict__ beta,
                                                 float* __restrict__ s_out, float* __restrict__ t_out) {
    __shared__ double lds_s[4][8], lds_q[4][8];
    int tid = threadIdx.x;
    int lane = tid & 63, wv = tid >> 6;
    int ol = lane & 7;
    int rg = wv * 8 + (lane >> 3);
    int o = blockIdx.x * 8 + ol;
    double s = 0.0, q = 0.0;
    for (int r = rg; r < 512; r += 32) {
        s += ps[(size_t)r * 512 + o];
        q += pq[(size_t)r * 512 + o];
    }
    s += __shfl_xor(s, 8);  q += __shfl_xor(q, 8);
    s += __shfl_xor(s, 16); q += __shfl_xor(q, 16);
    s += __shfl_xor(s, 32); q += __shfl_xor(q, 32);
    if (lane < 8) { lds_s[wv][ol] = s; lds_q[wv][ol] = q; }
    __syncthreads();
    if (tid < 8) {
        s = lds_s[0][tid] + lds_s[1][tid] + lds_s[2][tid] + lds_s[3][tid];
        q = lds_q[0][tid] + lds_q[1][tid] + lds_q[2][tid] + lds_q[3][tid];
        double invM = 1.0 / (BB * NN);
        double mean = s * invM;
        double var = q * invM - mean * mean;
        float inv = (float)(1.0 / sqrt(var + 1e-5));
        int oo = blockIdx.x * 8 + tid;
        float sc = g[oo] * inv;
        s_out[oo] = sc;
        t_out[oo] = beta[oo] - (float)mean * sc;
    }
}

// ---------------- per-batch max/min reduce + BN + lrelu -> feat8 (64 blocks) ----------------
__global__ __launch_bounds__(256) void featreduce_k(const float* __restrict__ pmax, const float* __restrict__ pmn,
                                                    const float* __restrict__ s, const float* __restrict__ t,
                                                    float* __restrict__ feat8) {
    __shared__ float smx[4][64], smn[4][64];
    int blk = blockIdx.x;
    int b = blk >> 3, oc = blk & 7;
    int tid = threadIdx.x;
    int lane = tid & 63, wv = tid >> 6;
    int o = oc * 64 + lane;
    float mx = -INFINITY, mn = INFINITY;
    for (int r = b * 64 + wv; r < (b + 1) * 64; r += 4) {
        mx = fmaxf(mx, pmax[(size_t)r * 512 + o]);
        mn = fminf(mn, pmn [(size_t)r * 512 + o]);
    }
    smx[wv][lane] = mx; smn[wv][lane] = mn;
    __syncthreads();
    if (wv == 0) {
        mx = fmaxf(fmaxf(smx[0][lane], smx[1][lane]), fmaxf(smx[2][lane], smx[3][lane]));
        mn = fminf(fminf(smn[0][lane], smn[1][lane]), fminf(smn[2][lane], smn[3][lane]));
        float sc = s[o];
        float v = sc >= 0.f ? mx : mn;
        float y = sc * v + t[o];
        feat8[(size_t)b * 512 + o] = y >= 0.f ? y : 0.2f * y;
    }
}

// ---------------- final gemm: out[8][256] = feat8 @ wemb^T (64 blocks, split-K) ----------------
__global__ __launch_bounds__(256) void outgemm_k(const float* __restrict__ feat8,
                                                 const float* __restrict__ wemb,
                                                 float* __restrict__ out) {
    __shared__ __align__(16) float feat[512];
    int blk = blockIdx.x;
    int b = blk >> 3, nc = blk & 7;
    int tid = threadIdx.x;
    for (int i = tid; i < 512; i += 256) feat[i] = feat8[(size_t)b * 512 + i];
    __syncthreads();
    int o_l = tid >> 3, kc = tid & 7;
    int o = nc * 32 + o_l;
    const float4* wr = (const float4*)(wemb + (size_t)o * 512 + kc * 64);
    const float4* fv = (const float4*)(feat + kc * 64);
    float acc = 0.f;
#pragma unroll
    for (int i = 0; i < 16; i++) {
        float4 wv = wr[i];
        float4 f  = fv[i];
        acc += wv.x * f.x + wv.y * f.y + wv.z * f.z + wv.w * f.w;
    }
    acc += __shfl_xor(acc, 1);
    acc += __shfl_xor(acc, 2);
    acc += __shfl_xor(acc, 4);
    if (kc == 0) out[(size_t)b * 256 + o] = acc;
}

extern "C" void kernel_launch(void* const* d_in, const int* in_sizes, int n_in,
                              void* d_out, int out_size, void* d_ws, size_t ws_size,
                              hipStream_t stream) {
    const float* x    = (const float*)d_in[0];
    const float* w1   = (const float*)d_in[1];
    const float* g1   = (const float*)d_in[2];
    const float* b1   = (const float*)d_in[3];
    const float* w2   = (const float*)d_in[4];
    const float* g2   = (const float*)d_in[5];
    const float* b2   = (const float*)d_in[6];
    const float* w3   = (const float*)d_in[7];
    const float* g3   = (const float*)d_in[8];
    const float* b3   = (const float*)d_in[9];
    const float* w4   = (const float*)d_in[10];
    const float* g4   = (const float*)d_in[11];
    const float* b4   = (const float*)d_in[12];
    const float* w5   = (const float*)d_in[13];
    const float* g5   = (const float*)d_in[14];
    const float* b5   = (const float*)d_in[15];
    const float* wemb = (const float*)d_in[16];
    float* out = (float*)d_out;

    float* fws    = (float*)d_ws;
    float* xtcat  = fws;                                 // 4,194,304
    float* ymax   = xtcat + (size_t)BB * NN * 512;       // 2,097,152
    float* ymin   = ymax + (size_t)BB * NN * 256;        // 2,097,152
    float* psum   = ymin + (size_t)BB * NN * 256;        // 2,097,152 (xT alias)
    float* psumsq = psum + (size_t)BB * NN * 256;        // 2,097,152 (spare; feat8 lives here at stage 5)
    float* xT     = psum;                                // alias
    float* pmax   = ymax;                                // alias: stage-5 partials
    float* pmn    = pmax + 512 * 512;
    float* ps5    = pmn + 512 * 512;
    float* pq5    = ps5 + 512 * 512;
    float* feat8  = psumsq;                              // 8*512 floats (stage-5 features)
    float* sqn    = psumsq + (size_t)BB * NN * 256;      // 8192
    float* s_arr  = sqn + BB * NN;                       // 512
    float* t_arr  = s_arr + 512;                         // 512
    float* r1s    = t_arr + 512;                         // 32*512
    float* r1q    = r1s + 32 * 512;                      // 32*512
    int*   idxb   = (int*)(r1q + 32 * 512);              // 8192*20 ints
    float* zfull  = (float*)(idxb + BB * NN * KNNK);     // 8192*512 fp32 (stages 1-3)
    __hip_bfloat16* zf4 = (__hip_bfloat16*)zfull;        // alias: stage-4 z, bf16
    __hip_bfloat16* xbf = (__hip_bfloat16*)(zfull + (size_t)BB * NN * 512);   // 8192*512 bf16

    const double invM_edge = 1.0 / ((double)BB * NN * KNNK);
    const int nbn = BB * NN;
    const int NK = nbn / 8;       // 1024 knn blocks (8 queries/block, 2/wave)
    const int NZ = nbn / 16;      // 512 zgemm blocks

    // ---- Stage 1 ----
    knn3_fused<<<NK, 256, 0, stream>>>(x, w1, zfull, idxb, r1s, r1q);
    gatherstats_k<128><<<nbn / 4, 256, 0, stream>>>(zfull, idxb, ymax, ymin, r1s, r1q);
    epitrans2_k<64><<<128, 256, 0, stream>>>(ymax, ymin, r1s, r1q, g1, b1, invM_edge, xtcat, 0, xT, sqn, xbf);

    // ---- Stage 2 ----
    knnz_fat<64, 128><<<NK + NZ, 256, 0, stream>>>(xT, xtcat, 0, sqn, idxb, w2, zfull, r1s, r1q, 64);
    gatherstats_k<128><<<nbn / 4, 256, 0, stream>>>(zfull, idxb, ymax, ymin, r1s, r1q);
    epitrans2_k<64><<<128, 256, 0, stream>>>(ymax, ymin, r1s, r1q, g2, b2, invM_edge, xtcat, 64, xT, sqn, xbf);

    // ---- Stage 3 ----
    knnz_fat<64, 256><<<NK + NZ, 256, 0, stream>>>(xT, xtcat, 64, sqn, idxb, w3, zfull, r1s, r1q, 128);
    gatherstats_k<256><<<nbn / 4, 256, 0, stream>>>(zfull, idxb, ymax, ymin, r1s, r1q);
    epitrans2_k<128><<<128, 256, 0, stream>>>(ymax, ymin, r1s, r1q, g3, b3, invM_edge, xtcat, 128, xT, sqn, xbf);

    // ---- Stage 4 (knn || zgemm4 in one fat launch) ----
    knnz4_fat<<<NK + 256, 256, 0, stream>>>(xT, sqn, idxb, xtcat, w4, zf4, r1s, r1q);
    gatherstats4_k<<<nbn / 4, 256, 0, stream>>>(zf4, idxb, ymax, ymin, r1s, r1q);
    epilogue4_k<<<256, 256, 0, stream>>>(ymax, ymin, r1s, r1q, g4, b4, invM_edge, xbf);

    // ---- Stage 5 ----
    gemm5_mfma<<<256, 256, 0, stream>>>(xbf, w5, pmax, pmn, ps5, pq5);
    bnstat5_k<<<64, 256, 0, stream>>>(ps5, pq5, g5, b5, s_arr, t_arr);
    featreduce_k<<<64, 256, 0, stream>>>(pmax, pmn, s_arr, t_arr, feat8);
    outgemm_k<<<64, 256, 0, stream>>>(feat8, wemb, out);
}

// Round 13
// 319.194 us; speedup vs baseline: 1.4928x; 1.0358x over previous
//
#include <hip/hip_runtime.h>
#include <hip/hip_bf16.h>
#include <math.h>

#define BB 8
#define NN 1024
#define KNNK 20
#define LDC 512

typedef __attribute__((ext_vector_type(8))) short bfrag8;
typedef __attribute__((ext_vector_type(4))) float facc4;
typedef __attribute__((ext_vector_type(2))) float v2f;

struct bh8 { __hip_bfloat16 h[8]; };

__device__ __forceinline__ bh8 cvt8(float4 a, float4 b) {
    bh8 v;
    v.h[0] = __float2bfloat16(a.x); v.h[1] = __float2bfloat16(a.y);
    v.h[2] = __float2bfloat16(a.z); v.h[3] = __float2bfloat16(a.w);
    v.h[4] = __float2bfloat16(b.x); v.h[5] = __float2bfloat16(b.y);
    v.h[6] = __float2bfloat16(b.z); v.h[7] = __float2bfloat16(b.w);
    return v;
}

// ---- DPP wave64 max reduce: 6 VALU-pipe steps, no ds_bpermute on the chain ----
template<int CTRL, int RMASK>
__device__ __forceinline__ float fmax_dpp(float x) {
    int xi = __float_as_int(x);
    int yi = __builtin_amdgcn_update_dpp(xi, xi, CTRL, RMASK, 0xF, false);
    return fmaxf(x, __int_as_float(yi));
}

__device__ __forceinline__ float wave_max64(float x) {
    x = fmax_dpp<0x121, 0xF>(x);   // row_ror:1
    x = fmax_dpp<0x122, 0xF>(x);   // row_ror:2
    x = fmax_dpp<0x124, 0xF>(x);   // row_ror:4
    x = fmax_dpp<0x128, 0xF>(x);   // row_ror:8  -> each lane = max of its row(16)
    x = fmax_dpp<0x142, 0xA>(x);   // row_bcast15 -> rows 1,3 combine with rows 0,2
    x = fmax_dpp<0x143, 0xC>(x);   // row_bcast31 -> lane63 = wave max
    return __int_as_float(__builtin_amdgcn_readlane(__float_as_int(x), 63));
}

// ---------------- top-20 selection: per-lane Batcher sort (regs) -> LDS write-back,
// merge with DPP wave-max + register head/prefetch (2 queries/wave, interleaved ILP) ----------------
__device__ __forceinline__ void select20_pf(float (*dist)[1024],
                                            int q0, int w, int lane,
                                            int* __restrict__ idxout) {
    float d[2][16];
    int   sl[2][16];
#pragma unroll
    for (int qi = 0; qi < 2; qi++) {
        int row = w * 2 + qi;
#pragma unroll
        for (int j = 0; j < 16; j++) { d[qi][j] = dist[row][lane + 64 * j]; sl[qi][j] = j; }
    }
    constexpr unsigned char CA[63] = {
        0,2,4,6,8,10,12,14,
        0,1,4,5,8,9,12,13,
        1,5,9,13,
        0,1,2,3,8,9,10,11,
        2,3,10,11,
        1,3,5,9,11,13,
        0,1,2,3,4,5,6,7,
        4,5,6,7,
        2,3,6,7,10,11,
        1,3,5,7,9,11,13};
    constexpr unsigned char CB[63] = {
        1,3,5,7,9,11,13,15,
        2,3,6,7,10,11,14,15,
        2,6,10,14,
        4,5,6,7,12,13,14,15,
        4,5,12,13,
        2,4,6,10,12,14,
        8,9,10,11,12,13,14,15,
        8,9,10,11,
        4,5,8,9,12,13,
        2,4,6,8,10,12,14};
#pragma unroll
    for (int c = 0; c < 63; c++) {
        const int a = CA[c], bq = CB[c];
#pragma unroll
        for (int qi = 0; qi < 2; qi++) {
            bool sw = d[qi][a] < d[qi][bq];
            float dmx = sw ? d[qi][bq] : d[qi][a];
            float dmn = sw ? d[qi][a]  : d[qi][bq];
            d[qi][a] = dmx; d[qi][bq] = dmn;
            int smx = sw ? sl[qi][bq] : sl[qi][a];
            int smn = sw ? sl[qi][a]  : sl[qi][bq];
            sl[qi][a] = smx; sl[qi][bq] = smn;
        }
    }
    // write sorted values back to LDS (backing store for deep refills) and pack the
    // slot queue into one u64 per query (4 bits/slot).
    unsigned long long slp[2];
#pragma unroll
    for (int qi = 0; qi < 2; qi++) {
        int row = w * 2 + qi;
#pragma unroll
        for (int j = 0; j < 16; j++) dist[row][j * 64 + lane] = d[qi][j];
        unsigned long long p = 0;
#pragma unroll
        for (int j = 0; j < 16; j++) p |= (unsigned long long)sl[qi][j] << (4 * j);
        slp[qi] = p;
    }
    // merge state: head + one prefetched value per query; refill loads issued by the
    // winner right after consumption -> latency hidden behind the next round's reduce.
    float head[2] = {d[0][0], d[1][0]};
    float pf[2]   = {d[0][1], d[1][1]};
    int   ptr[2]  = {2, 2};
    for (int t = 0; t < KNNK; t++) {
#pragma unroll
        for (int qi = 0; qi < 2; qi++) {
            int row = w * 2 + qi;
            float bv = wave_max64(head[qi]);
            unsigned long long ball = __ballot(head[qi] == bv);
            int wl = (int)__builtin_ctzll(ball);
            bool win = (lane == wl);
            if (win) {
                idxout[(q0 + row) * KNNK + t] = (int)(slp[qi] & 15ull) * 64 + lane;
            }
            head[qi] = win ? pf[qi] : head[qi];
            slp[qi]  = win ? (slp[qi] >> 4) : slp[qi];
            if (win) {
                int p = ptr[qi];
                pf[qi] = (p < 16) ? dist[row][p * 64 + lane] : -INFINITY;
                ptr[qi] = p + 1;
            }
        }
    }
}

// r1 zeroing helper (duplicate zero-writes with >256 threads are benign)
__device__ __forceinline__ void zero_r1(float* r1s, float* r1q, int O, int tid) {
    for (int i = tid; i < 32 * O; i += 256) { r1s[i] = 0.f; r1q[i] = 0.f; }
}

// ---------------- fused kNN stage 1 (C=3) + stage-1 z-gemm, 8 queries/block (256 thr) ----------------
__global__ __launch_bounds__(256, 4) void knn3_fused(const float* __restrict__ x,
                                                     const float* __restrict__ w1,
                                                     float* __restrict__ zf,
                                                     int* __restrict__ idxout,
                                                     float* __restrict__ r1s, float* __restrict__ r1q) {
    __shared__ float dist[8][1024];
    int tid = threadIdx.x;
    int q0 = (blockIdx.x & 7) * 1024 + (blockIdx.x >> 3) * 8;   // XCD swizzle
    int b = q0 >> 10;
    if (blockIdx.x == 0) zero_r1(r1s, r1q, 64, tid);
    const float* xb = x + (size_t)b * NN * 3;
    int lane = tid & 63, w = tid >> 6;
    float qx[8], qy[8], qz[8];
#pragma unroll
    for (int q = 0; q < 8; q++) {
        const float* qr = xb + (size_t)((q0 & (NN - 1)) + q) * 3;
        qx[q] = qr[0]; qy[q] = qr[1]; qz[q] = qr[2];
    }
#pragma unroll
    for (int cq = 0; cq < 4; cq++) {
        int cand = w * 256 + cq * 64 + lane;
        const float* cr = xb + (size_t)cand * 3;
        float cx = cr[0], cy = cr[1], cz = cr[2];
        float sqc = cx * cx + cy * cy + cz * cz;
#pragma unroll
        for (int q = 0; q < 8; q++) {
            float d = qx[q] * cx + qy[q] * cy + qz[q] * cz;
            dist[q][cand] = 2.f * d - sqc;
        }
    }
    for (int i = tid; i < 8 * 128; i += 256) {
        int lq = i >> 7, j = i & 127;
        const float* wr = w1 + (j < 64 ? j * 6 : (j - 64) * 6 + 3);
        const float* xr = x + (size_t)(q0 + lq) * 3;
        zf[(size_t)(q0 + lq) * 128 + j] = wr[0] * xr[0] + wr[1] * xr[1] + wr[2] * xr[2];
    }
    __syncthreads();
    select20_pf(dist, q0, w, lane, idxout);
}

// ---------------- knn core (stages 2-4): 512 threads, 16 queries/block, 2 q/wave,
// 2 candidates/thread (panel traffic halved), 8 channels/iter (in-flight bytes kept) ----------------
template<int C>
__device__ __forceinline__ void knn_body16w(const float* __restrict__ xT,
                                            const float* __restrict__ sqn,
                                            int* __restrict__ idxout,
                                            float (*dist)[1024], int knnBlk) {
    int tid = threadIdx.x;                 // 0..511
    int q0 = (knnBlk & 7) * 1024 + (knnBlk >> 3) * 16;          // XCD swizzle
    int b = q0 >> 10;
    int lane = tid & 63, w = tid >> 6;     // 8 waves, wave w owns queries 2w,2w+1
    int cand0 = 2 * tid;                   // 2 candidates/thread
    const float* xTb = xT + (size_t)b * C * 1024;
    const float* qrow = xTb + (q0 & (NN - 1));                  // block-uniform base
    float2 sq2 = *(const float2*)(sqn + b * NN + cand0);
    v2f acc2[8][2];                        // [query-pair][candidate]
#pragma unroll
    for (int k = 0; k < 8; k++) { acc2[k][0] = (v2f){0.f, 0.f}; acc2[k][1] = (v2f){0.f, 0.f}; }
    for (int cg = 0; cg < C / 8; cg++) {
        float2 rch[8];
#pragma unroll
        for (int c = 0; c < 8; c++)
            rch[c] = *(const float2*)(xTb + (size_t)(8 * cg + c) * 1024 + cand0);
#pragma unroll
        for (int c = 0; c < 8; c++) {
            const float* qr = qrow + (size_t)(8 * cg + c) * 1024;
            float4 qa = *(const float4*)qr;                     // uniform -> s_load (16 queries)
            float4 qb = *(const float4*)(qr + 4);
            float4 qc = *(const float4*)(qr + 8);
            float4 qd = *(const float4*)(qr + 12);
            v2f qp[8] = {{qa.x, qa.y}, {qa.z, qa.w}, {qb.x, qb.y}, {qb.z, qb.w},
                         {qc.x, qc.y}, {qc.z, qc.w}, {qd.x, qd.y}, {qd.z, qd.w}};
            v2f r0 = {rch[c].x, rch[c].x};
            v2f r1 = {rch[c].y, rch[c].y};
#pragma unroll
            for (int k = 0; k < 8; k++) {
                acc2[k][0] += qp[k] * r0;
                acc2[k][1] += qp[k] * r1;
            }
        }
    }
#pragma unroll
    for (int k = 0; k < 8; k++)
#pragma unroll
        for (int half = 0; half < 2; half++) {
            int q = 2 * k + half;
            float2 dv;
            dv.x = 2.f * acc2[k][0][half] - sq2.x;
            dv.y = 2.f * acc2[k][1][half] - sq2.y;
            *(float2*)&dist[q][cand0] = dv;
        }
    __syncthreads();
    select20_pf(dist, q0, w, lane, idxout);
}

// ---------------- FAT kernel stages 2-3 (512 thr): knn 16q (blocks<512) + zgemm (blocks>=512) ----------------
template<int C, int ZO2>
__global__ __launch_bounds__(512, 4) void knnz_fat(const float* __restrict__ xT,
                                                   const float* __restrict__ xt, int off,
                                                   const float* __restrict__ sqn,
                                                   int* __restrict__ idxout,
                                                   const float* __restrict__ w,
                                                   float* __restrict__ zf,
                                                   float* __restrict__ r1s, float* __restrict__ r1q,
                                                   int Onext) {
    __shared__ float dist[16][1024];
    int tid = threadIdx.x;
    if ((int)blockIdx.x < BB * NN / 16) {
        knn_body16w<C>(xT, sqn, idxout, dist, blockIdx.x);
        return;
    }
    // ---- zgemm path (threads >=256 idle in the bounded loops) ----
    constexpr int ZO = ZO2 / 2;
    int zblk = blockIdx.x - BB * NN / 16;
    if (zblk == 0) zero_r1(r1s, r1q, Onext, tid);
    float (*xs)[C] = (float (*)[C])&dist[0][0];
    int p0 = zblk * 16;
    for (int j = tid; j < 16 * (C / 4); j += 256) {
        int p = j / (C / 4), c4 = j % (C / 4);
        *(float4*)&xs[p][4 * c4] = *(const float4*)(xt + (size_t)(p0 + p) * LDC + off + 4 * c4);
    }
    __syncthreads();
    for (int j = tid; j < ZO2; j += 256) {
        const float* wr = w + (j < ZO ? (size_t)j * 2 * C : (size_t)(j - ZO) * 2 * C + C);
        float acc[16];
#pragma unroll
        for (int p = 0; p < 16; p++) acc[p] = 0.f;
        for (int c4 = 0; c4 < C / 4; c4++) {
            float4 wv = *(const float4*)(wr + 4 * c4);
#pragma unroll
            for (int p = 0; p < 16; p++) {
                float4 xv = *(const float4*)&xs[p][4 * c4];
                acc[p] += wv.x * xv.x + wv.y * xv.y + wv.z * xv.z + wv.w * xv.w;
            }
        }
#pragma unroll
        for (int p = 0; p < 16; p++) zf[(size_t)(p0 + p) * ZO2 + j] = acc[p];
    }
}

// ---------------- FAT stage 4 (512 thr): knn<128> 16q (blocks<512) + bf16 MFMA zgemm (blocks>=512) ----------------
__global__ __launch_bounds__(512, 4) void knnz4_fat(const float* __restrict__ xT,
                                                    const float* __restrict__ sqn,
                                                    int* __restrict__ idxout,
                                                    const float* __restrict__ xtcat,
                                                    const float* __restrict__ w4,
                                                    __hip_bfloat16* __restrict__ zf4,
                                                    float* __restrict__ r1s, float* __restrict__ r1q) {
    __shared__ __align__(16) char smem[65536];
    int tid = threadIdx.x;
    if ((int)blockIdx.x < BB * NN / 16) {
        float (*dist)[1024] = (float (*)[1024])smem;
        if (blockIdx.x == 0) zero_r1(r1s, r1q, 256, tid);
        knn_body16w<128>(xT, sqn, idxout, dist, blockIdx.x);
        return;
    }
    // ---- zgemm4 path (bf16 MFMA), active threads = tid<256; barriers involve all ----
    __hip_bfloat16 (*A)[72] = (__hip_bfloat16 (*)[72])smem;
    __hip_bfloat16 (*W)[72] = (__hip_bfloat16 (*)[72])(smem + 18432);
    bool zact = tid < 256;
    int zblk = blockIdx.x - BB * NN / 16;
    int mt = zblk >> 2, nt = zblk & 3;
    int lane = tid & 63, wvx = tid >> 6;
    int mw = (wvx >> 1) & 1, nw = wvx & 1;
    int m0 = lane & 15, qd = lane >> 4;
    int r = tid & 127, hf = (tid >> 7) & 1;
    facc4 acc[4][4];
    facc4 zz = {0.f, 0.f, 0.f, 0.f};
#pragma unroll
    for (int mi = 0; mi < 4; mi++)
#pragma unroll
        for (int ni = 0; ni < 4; ni++) acc[mi][ni] = zz;
    int j = nt * 128 + r;
    const float* wsrc = w4 + (j < 256 ? (size_t)j * 256 : (size_t)(j - 256) * 256 + 128);
    const float* asrc = xtcat + (size_t)(mt * 128 + r) * 512 + 128;
    for (int kc = 0; kc < 2; kc++) {
        if (zact) {
#pragma unroll
            for (int u = 0; u < 4; u++) {
                int c0 = kc * 64 + hf * 32 + 8 * u;
                float4 a0 = *(const float4*)(asrc + c0);
                float4 a1 = *(const float4*)(asrc + c0 + 4);
                *(bh8*)&A[r][hf * 32 + 8 * u] = cvt8(a0, a1);
                float4 w0 = *(const float4*)(wsrc + c0);
                float4 w1 = *(const float4*)(wsrc + c0 + 4);
                *(bh8*)&W[r][hf * 32 + 8 * u] = cvt8(w0, w1);
            }
        }
        __syncthreads();
        if (zact) {
#pragma unroll
            for (int kk = 0; kk < 2; kk++) {
                bfrag8 af[4], bf[4];
#pragma unroll
                for (int mi = 0; mi < 4; mi++)
                    af[mi] = *(const bfrag8*)&A[64 * mw + 16 * mi + m0][32 * kk + 8 * qd];
#pragma unroll
                for (int ni = 0; ni < 4; ni++)
                    bf[ni] = *(const bfrag8*)&W[64 * nw + 16 * ni + m0][32 * kk + 8 * qd];
#pragma unroll
                for (int mi = 0; mi < 4; mi++)
#pragma unroll
                    for (int ni = 0; ni < 4; ni++)
                        acc[mi][ni] = __builtin_amdgcn_mfma_f32_16x16x32_bf16(af[mi], bf[ni], acc[mi][ni], 0, 0, 0);
            }
        }
        __syncthreads();
    }
    if (zact) {
#pragma unroll
        for (int mi = 0; mi < 4; mi++)
#pragma unroll
            for (int ni = 0; ni < 4; ni++)
#pragma unroll
                for (int rg = 0; rg < 4; rg++) {
                    int row = mt * 128 + mw * 64 + mi * 16 + qd * 4 + rg;
                    int col = nt * 128 + nw * 64 + ni * 16 + m0;
                    zf4[(size_t)row * 512 + col] = __float2bfloat16(acc[mi][ni][rg]);
                }
    }
}

// ---------------- gather + stats (fp32 zf, stages 1-3): in-block reduce + atomics ----------------
template<int O2>
__global__ __launch_bounds__(256) void gatherstats_k(const float* __restrict__ zf,
                                                     const int* __restrict__ idx,
                                                     float* __restrict__ ymax, float* __restrict__ ymin,
                                                     float* __restrict__ r1s, float* __restrict__ r1q) {
    constexpr int O = O2 / 2;
    __shared__ float red_s[4][O], red_q[4][O];
    int wv = threadIdx.x >> 6, lane = threadIdx.x & 63;
    int n = (blockIdx.x & 7) * 1024 + (blockIdx.x >> 3) * 4 + wv;   // XCD swizzle
    int b = n >> 10;
    const float* zbatch = zf + (size_t)b * NN * O2;
    int nb[KNNK];
#pragma unroll
    for (int k = 0; k < KNNK; k++) nb[k] = idx[n * KNNK + k];
#pragma unroll
    for (int ch = 0; ch < O / 64; ch++) {
        int o = ch * 64 + lane;
        float g[KNNK];
#pragma unroll
        for (int k = 0; k < KNNK; k++) g[k] = zbatch[(size_t)nb[k] * O2 + o];
        float mx = -INFINITY, mn = INFINITY, s = 0.f, ss = 0.f;
#pragma unroll
        for (int k = 0; k < KNNK; k++) {
            float v = g[k];
            mx = fmaxf(mx, v); mn = fminf(mn, v); s += v; ss += v * v;
        }
        float zn  = zf[(size_t)n * O2 + o];
        float zbn = zf[(size_t)n * O2 + O + o];
        float d = zbn - zn;
        mx += d; mn += d;
        ss = ss + 2.f * d * s + (float)KNNK * d * d;
        s  = s + (float)KNNK * d;
        ymax[(size_t)n * O + o] = mx;
        ymin[(size_t)n * O + o] = mn;
        red_s[wv][o] = s;
        red_q[wv][o] = ss;
    }
    __syncthreads();
    int bucket = blockIdx.x & 31;
    for (int o = threadIdx.x; o < O; o += 256) {
        float s4 = red_s[0][o] + red_s[1][o] + red_s[2][o] + red_s[3][o];
        float q4 = red_q[0][o] + red_q[1][o] + red_q[2][o] + red_q[3][o];
        atomicAdd(&r1s[(size_t)bucket * O + o], s4);
        atomicAdd(&r1q[(size_t)bucket * O + o], q4);
    }
}

// ---------------- gather + stats, bf16 zf4 (stage 4) ----------------
__global__ __launch_bounds__(256) void gatherstats4_k(const __hip_bfloat16* __restrict__ zf4,
                                                      const int* __restrict__ idx,
                                                      float* __restrict__ ymax, float* __restrict__ ymin,
                                                      float* __restrict__ r1s, float* __restrict__ r1q) {
    __shared__ float red_s[4][256], red_q[4][256];
    int wv = threadIdx.x >> 6, lane = threadIdx.x & 63;
    int n = (blockIdx.x & 7) * 1024 + (blockIdx.x >> 3) * 4 + wv;
    int b = n >> 10;
    const __hip_bfloat16* zbatch = zf4 + (size_t)b * NN * 512;
    int nb[KNNK];
#pragma unroll
    for (int k = 0; k < KNNK; k++) nb[k] = idx[n * KNNK + k];
#pragma unroll
    for (int ch = 0; ch < 4; ch++) {
        int o = ch * 64 + lane;
        float g[KNNK];
#pragma unroll
        for (int k = 0; k < KNNK; k++) g[k] = __bfloat162float(zbatch[(size_t)nb[k] * 512 + o]);
        float mx = -INFINITY, mn = INFINITY, s = 0.f, ss = 0.f;
#pragma unroll
        for (int k = 0; k < KNNK; k++) {
            float v = g[k];
            mx = fmaxf(mx, v); mn = fminf(mn, v); s += v; ss += v * v;
        }
        float zn  = __bfloat162float(zf4[(size_t)n * 512 + o]);
        float zbn = __bfloat162float(zf4[(size_t)n * 512 + 256 + o]);
        float d = zbn - zn;
        mx += d; mn += d;
        ss = ss + 2.f * d * s + (float)KNNK * d * d;
        s  = s + (float)KNNK * d;
        ymax[(size_t)n * 256 + o] = mx;
        ymin[(size_t)n * 256 + o] = mn;
        red_s[wv][o] = s;
        red_q[wv][o] = ss;
    }
    __syncthreads();
    int bucket = blockIdx.x & 31;
    for (int o = threadIdx.x; o < 256; o += 256) {
        float s4 = red_s[0][o] + red_s[1][o] + red_s[2][o] + red_s[3][o];
        float q4 = red_q[0][o] + red_q[1][o] + red_q[2][o] + red_q[3][o];
        atomicAdd(&r1s[(size_t)bucket * 256 + o], s4);
        atomicAdd(&r1q[(size_t)bucket * 256 + o], q4);
    }
}

// ---------------- BN+lrelu epilogue + transpose + |c|^2 + bf16 copy, s/t computed in-block ----------------
template<int O>
__global__ __launch_bounds__(256) void epitrans2_k(const float* __restrict__ ymax, const float* __restrict__ ymin,
                                                   const float* __restrict__ r1s, const float* __restrict__ r1q,
                                                   const float* __restrict__ g, const float* __restrict__ beta,
                                                   double invM,
                                                   float* __restrict__ xtcat, int off_out,
                                                   float* __restrict__ xT, float* __restrict__ sqn,
                                                   __hip_bfloat16* __restrict__ xbf) {
    __shared__ float tile[64][O + 1];
    __shared__ float ssh[O], tth[O];
    int n0 = blockIdx.x * 64;
    int b = n0 >> 10;
    int tid = threadIdx.x;
    for (int o = tid; o < O; o += 256) {
        double sd = 0.0, qd = 0.0;
        for (int r = 0; r < 32; r++) { sd += r1s[(size_t)r * O + o]; qd += r1q[(size_t)r * O + o]; }
        double mean = sd * invM;
        double var = qd * invM - mean * mean;
        float inv = (float)(1.0 / sqrt(var + 1e-5));
        float sc = g[o] * inv;
        ssh[o] = sc;
        tth[o] = beta[o] - (float)mean * sc;
    }
    __syncthreads();
    for (int i = tid; i < 64 * O; i += 256) {
        int nl = i / O;
        int o = i & (O - 1);
        int n = n0 + nl;
        float sc = ssh[o];
        float v = sc >= 0.f ? ymax[(size_t)n * O + o] : ymin[(size_t)n * O + o];
        float y = sc * v + tth[o];
        y = y >= 0.f ? y : 0.2f * y;
        xtcat[(size_t)n * LDC + off_out + o] = y;
        xbf[(size_t)n * LDC + off_out + o] = __float2bfloat16(y);
        tile[nl][o] = y;
    }
    __syncthreads();
    if (tid < 64) {
        float sq = 0.f;
        for (int c = 0; c < O; c++) { float v = tile[tid][c]; sq += v * v; }
        sqn[n0 + tid] = sq;
    }
    int r = tid >> 4, cq = tid & 15;
#pragma unroll
    for (int ct = 0; ct < O / 16; ct++) {
        int c = ct * 16 + r;
        float4 ov;
        ov.x = tile[4 * cq + 0][c];
        ov.y = tile[4 * cq + 1][c];
        ov.z = tile[4 * cq + 2][c];
        ov.w = tile[4 * cq + 3][c];
        *(float4*)(xT + ((size_t)b * O + c) * 1024 + (n0 & (NN - 1)) + 4 * cq) = ov;
    }
}

// ---------------- stage-4 epilogue: s/t in-block, writes xbf ONLY (256 blocks x 32 rows) ----------------
__global__ __launch_bounds__(256) void epilogue4_k(const float* __restrict__ ymax, const float* __restrict__ ymin,
                                                   const float* __restrict__ r1s, const float* __restrict__ r1q,
                                                   const float* __restrict__ g, const float* __restrict__ beta,
                                                   double invM,
                                                   __hip_bfloat16* __restrict__ xbf) {
    __shared__ float ssh[256], tth[256];
    int n0 = blockIdx.x * 32;
    int tid = threadIdx.x;
    {
        int o = tid;
        double sd = 0.0, qd = 0.0;
        for (int r = 0; r < 32; r++) { sd += r1s[(size_t)r * 256 + o]; qd += r1q[(size_t)r * 256 + o]; }
        double mean = sd * invM;
        double var = qd * invM - mean * mean;
        float inv = (float)(1.0 / sqrt(var + 1e-5));
        float sc = g[o] * inv;
        ssh[o] = sc;
        tth[o] = beta[o] - (float)mean * sc;
    }
    __syncthreads();
    for (int i = tid; i < 32 * 256; i += 256) {
        int nl = i >> 8;
        int o = i & 255;
        int n = n0 + nl;
        float sc = ssh[o];
        float v = sc >= 0.f ? ymax[(size_t)n * 256 + o] : ymin[(size_t)n * 256 + o];
        float y = sc * v + tth[o];
        y = y >= 0.f ? y : 0.2f * y;
        xbf[(size_t)n * LDC + 256 + o] = __float2bfloat16(y);
    }
}

// ---------------- stage 5: bf16 MFMA GEMM (W staged from fp32 w5) w/ fused stats ----------------
__global__ __launch_bounds__(256) void gemm5_mfma(const __hip_bfloat16* __restrict__ xbf,
                                                  const float* __restrict__ w5,
                                                  float* __restrict__ pmax, float* __restrict__ pmn,
                                                  float* __restrict__ ps, float* __restrict__ pq) {
    __shared__ __hip_bfloat16 A[128][72];
    __shared__ __hip_bfloat16 W[128][72];
    int mt = blockIdx.x >> 2, nt = blockIdx.x & 3;
    int tid = threadIdx.x;
    int lane = tid & 63, wvx = tid >> 6;
    int mw = wvx >> 1, nw = wvx & 1;
    int m0 = lane & 15, qd = lane >> 4;
    int r = tid & 127, hf = tid >> 7;
    facc4 acc[4][4];
    facc4 zz = {0.f, 0.f, 0.f, 0.f};
#pragma unroll
    for (int mi = 0; mi < 4; mi++)
#pragma unroll
        for (int ni = 0; ni < 4; ni++) acc[mi][ni] = zz;
    for (int kc = 0; kc < 8; kc++) {
        const __hip_bfloat16* ap = xbf + (size_t)(mt * 128 + r) * 512 + kc * 64 + hf * 32;
        const float* wp = w5 + (size_t)(nt * 128 + r) * 512 + kc * 64 + hf * 32;
#pragma unroll
        for (int u = 0; u < 4; u++) {
            bh8 av = *(const bh8*)(ap + 8 * u);
            *(bh8*)&A[r][hf * 32 + 8 * u] = av;
            float4 w0 = *(const float4*)(wp + 8 * u);
            float4 w1 = *(const float4*)(wp + 8 * u + 4);
            *(bh8*)&W[r][hf * 32 + 8 * u] = cvt8(w0, w1);
        }
        __syncthreads();
#pragma unroll
        for (int kk = 0; kk < 2; kk++) {
            bfrag8 af[4], bf[4];
#pragma unroll
            for (int mi = 0; mi < 4; mi++)
                af[mi] = *(const bfrag8*)&A[64 * mw + 16 * mi + m0][32 * kk + 8 * qd];
#pragma unroll
            for (int ni = 0; ni < 4; ni++)
                bf[ni] = *(const bfrag8*)&W[64 * nw + 16 * ni + m0][32 * kk + 8 * qd];
#pragma unroll
            for (int mi = 0; mi < 4; mi++)
#pragma unroll
                for (int ni = 0; ni < 4; ni++)
                    acc[mi][ni] = __builtin_amdgcn_mfma_f32_16x16x32_bf16(af[mi], bf[ni], acc[mi][ni], 0, 0, 0);
        }
        __syncthreads();
    }
#pragma unroll
    for (int mi = 0; mi < 4; mi++) {
        int grp = mt * 8 + mw * 4 + mi;
#pragma unroll
        for (int ni = 0; ni < 4; ni++) {
            float mx = -INFINITY, mn = INFINITY, s = 0.f, ss = 0.f;
#pragma unroll
            for (int rg = 0; rg < 4; rg++) {
                float v = acc[mi][ni][rg];
                mx = fmaxf(mx, v); mn = fminf(mn, v); s += v; ss += v * v;
            }
#pragma unroll
            for (int m = 16; m < 64; m <<= 1) {
                mx = fmaxf(mx, __shfl_xor(mx, m));
                mn = fminf(mn, __shfl_xor(mn, m));
                s += __shfl_xor(s, m);
                ss += __shfl_xor(ss, m);
            }
            if (qd == 0) {
                int o = nt * 128 + nw * 64 + ni * 16 + m0;
                pmax[(size_t)grp * 512 + o] = mx;
                pmn [(size_t)grp * 512 + o] = mn;
                ps  [(size_t)grp * 512 + o] = s;
                pq  [(size_t)grp * 512 + o] = ss;
            }
        }
    }
}

// ---------------- stage-5 BN stats: 64 blocks x 8 channels ----------------
__global__ __launch_bounds__(256) void bnstat5_k(const float* __restrict__ ps, const float* __restrict__ pq,
                                                 const float* __restrict__ g, const float* __restrict__ beta,
                                                 float* __restrict__ s_out, float* __restrict__ t_out) {
    __shared__ double lds_s[4][8], lds_q[4][8];
    int tid = threadIdx.x;
    int lane = tid & 63, wv = tid >> 6;
    int ol = lane & 7;
    int rg = wv * 8 + (lane >> 3);
    int o = blockIdx.x * 8 + ol;
    double s = 0.0, q = 0.0;
    for (int r = rg; r < 512; r += 32) {
        s += ps[(size_t)r * 512 + o];
        q += pq[(size_t)r * 512 + o];
    }
    s += __shfl_xor(s, 8);  q += __shfl_xor(q, 8);
    s += __shfl_xor(s, 16); q += __shfl_xor(q, 16);
    s += __shfl_xor(s, 32); q += __shfl_xor(q, 32);
    if (lane < 8) { lds_s[wv][ol] = s; lds_q[wv][ol] = q; }
    __syncthreads();
    if (tid < 8) {
        s = lds_s[0][tid] + lds_s[1][tid] + lds_s[2][tid] + lds_s[3][tid];
        q = lds_q[0][tid] + lds_q[1][tid] + lds_q[2][tid] + lds_q[3][tid];
        double invM = 1.0 / (BB * NN);
        double mean = s * invM;
        double var = q * invM - mean * mean;
        float inv = (float)(1.0 / sqrt(var + 1e-5));
        int oo = blockIdx.x * 8 + tid;
        float sc = g[oo] * inv;
        s_out[oo] = sc;
        t_out[oo] = beta[oo] - (float)mean * sc;
    }
}

// ---------------- per-batch max/min reduce + BN + lrelu -> feat8 (64 blocks) ----------------
__global__ __launch_bounds__(256) void featreduce_k(const float* __restrict__ pmax, const float* __restrict__ pmn,
                                                    const float* __restrict__ s, const float* __restrict__ t,
                                                    float* __restrict__ feat8) {
    __shared__ float smx[4][64], smn[4][64];
    int blk = blockIdx.x;
    int b = blk >> 3, oc = blk & 7;
    int tid = threadIdx.x;
    int lane = tid & 63, wv = tid >> 6;
    int o = oc * 64 + lane;
    float mx = -INFINITY, mn = INFINITY;
    for (int r = b * 64 + wv; r < (b + 1) * 64; r += 4) {
        mx = fmaxf(mx, pmax[(size_t)r * 512 + o]);
        mn = fminf(mn, pmn [(size_t)r * 512 + o]);
    }
    smx[wv][lane] = mx; smn[wv][lane] = mn;
    __syncthreads();
    if (wv == 0) {
        mx = fmaxf(fmaxf(smx[0][lane], smx[1][lane]), fmaxf(smx[2][lane], smx[3][lane]));
        mn = fminf(fminf(smn[0][lane], smn[1][lane]), fminf(smn[2][lane], smn[3][lane]));
        float sc = s[o];
        float v = sc >= 0.f ? mx : mn;
        float y = sc * v + t[o];
        feat8[(size_t)b * 512 + o] = y >= 0.f ? y : 0.2f * y;
    }
}

// ---------------- final gemm: out[8][256] = feat8 @ wemb^T (64 blocks, split-K) ----------------
__global__ __launch_bounds__(256) void outgemm_k(const float* __restrict__ feat8,
                                                 const float* __restrict__ wemb,
                                                 float* __restrict__ out) {
    __shared__ __align__(16) float feat[512];
    int blk = blockIdx.x;
    int b = blk >> 3, nc = blk & 7;
    int tid = threadIdx.x;
    for (int i = tid; i < 512; i += 256) feat[i] = feat8[(size_t)b * 512 + i];
    __syncthreads();
    int o_l = tid >> 3, kc = tid & 7;
    int o = nc * 32 + o_l;
    const float4* wr = (const float4*)(wemb + (size_t)o * 512 + kc * 64);
    const float4* fv = (const float4*)(feat + kc * 64);
    float acc = 0.f;
#pragma unroll
    for (int i = 0; i < 16; i++) {
        float4 wv = wr[i];
        float4 f  = fv[i];
        acc += wv.x * f.x + wv.y * f.y + wv.z * f.z + wv.w * f.w;
    }
    acc += __shfl_xor(acc, 1);
    acc += __shfl_xor(acc, 2);
    acc += __shfl_xor(acc, 4);
    if (kc == 0) out[(size_t)b * 256 + o] = acc;
}

extern "C" void kernel_launch(void* const* d_in, const int* in_sizes, int n_in,
                              void* d_out, int out_size, void* d_ws, size_t ws_size,
                              hipStream_t stream) {
    const float* x    = (const float*)d_in[0];
    const float* w1   = (const float*)d_in[1];
    const float* g1   = (const float*)d_in[2];
    const float* b1   = (const float*)d_in[3];
    const float* w2   = (const float*)d_in[4];
    const float* g2   = (const float*)d_in[5];
    const float* b2   = (const float*)d_in[6];
    const float* w3   = (const float*)d_in[7];
    const float* g3   = (const float*)d_in[8];
    const float* b3   = (const float*)d_in[9];
    const float* w4   = (const float*)d_in[10];
    const float* g4   = (const float*)d_in[11];
    const float* b4   = (const float*)d_in[12];
    const float* w5   = (const float*)d_in[13];
    const float* g5   = (const float*)d_in[14];
    const float* b5   = (const float*)d_in[15];
    const float* wemb = (const float*)d_in[16];
    float* out = (float*)d_out;

    float* fws    = (float*)d_ws;
    float* xtcat  = fws;                                 // 4,194,304
    float* ymax   = xtcat + (size_t)BB * NN * 512;       // 2,097,152
    float* ymin   = ymax + (size_t)BB * NN * 256;        // 2,097,152
    float* psum   = ymin + (size_t)BB * NN * 256;        // 2,097,152 (xT alias)
    float* psumsq = psum + (size_t)BB * NN * 256;        // 2,097,152 (spare; feat8 lives here at stage 5)
    float* xT     = psum;                                // alias
    float* pmax   = ymax;                                // alias: stage-5 partials
    float* pmn    = pmax + 512 * 512;
    float* ps5    = pmn + 512 * 512;
    float* pq5    = ps5 + 512 * 512;
    float* feat8  = psumsq;                              // 8*512 floats (stage-5 features)
    float* sqn    = psumsq + (size_t)BB * NN * 256;      // 8192
    float* s_arr  = sqn + BB * NN;                       // 512
    float* t_arr  = s_arr + 512;                         // 512
    float* r1s    = t_arr + 512;                         // 32*512
    float* r1q    = r1s + 32 * 512;                      // 32*512
    int*   idxb   = (int*)(r1q + 32 * 512);              // 8192*20 ints
    float* zfull  = (float*)(idxb + BB * NN * KNNK);     // 8192*512 fp32 (stages 1-3)
    __hip_bfloat16* zf4 = (__hip_bfloat16*)zfull;        // alias: stage-4 z, bf16
    __hip_bfloat16* xbf = (__hip_bfloat16*)(zfull + (size_t)BB * NN * 512);   // 8192*512 bf16

    const double invM_edge = 1.0 / ((double)BB * NN * KNNK);
    const int nbn = BB * NN;
    const int NK   = nbn / 8;     // 1024 knn blocks (stage 1, 8 q/block, 256 thr)
    const int NK16 = nbn / 16;    // 512 knn blocks (stages 2-4, 16 q/block, 512 thr)
    const int NZ   = nbn / 16;    // 512 zgemm blocks

    // ---- Stage 1 ----
    knn3_fused<<<NK, 256, 0, stream>>>(x, w1, zfull, idxb, r1s, r1q);
    gatherstats_k<128><<<nbn / 4, 256, 0, stream>>>(zfull, idxb, ymax, ymin, r1s, r1q);
    epitrans2_k<64><<<128, 256, 0, stream>>>(ymax, ymin, r1s, r1q, g1, b1, invM_edge, xtcat, 0, xT, sqn, xbf);

    // ---- Stage 2 ----
    knnz_fat<64, 128><<<NK16 + NZ, 512, 0, stream>>>(xT, xtcat, 0, sqn, idxb, w2, zfull, r1s, r1q, 64);
    gatherstats_k<128><<<nbn / 4, 256, 0, stream>>>(zfull, idxb, ymax, ymin, r1s, r1q);
    epitrans2_k<64><<<128, 256, 0, stream>>>(ymax, ymin, r1s, r1q, g2, b2, invM_edge, xtcat, 64, xT, sqn, xbf);

    // ---- Stage 3 ----
    knnz_fat<64, 256><<<NK16 + NZ, 512, 0, stream>>>(xT, xtcat, 64, sqn, idxb, w3, zfull, r1s, r1q, 128);
    gatherstats_k<256><<<nbn / 4, 256, 0, stream>>>(zfull, idxb, ymax, ymin, r1s, r1q);
    epitrans2_k<128><<<128, 256, 0, stream>>>(ymax, ymin, r1s, r1q, g3, b3, invM_edge, xtcat, 128, xT, sqn, xbf);

    // ---- Stage 4 (knn 16q || zgemm4 in one fat launch, 512 threads) ----
    knnz4_fat<<<NK16 + 256, 512, 0, stream>>>(xT, sqn, idxb, xtcat, w4, zf4, r1s, r1q);
    gatherstats4_k<<<nbn / 4, 256, 0, stream>>>(zf4, idxb, ymax, ymin, r1s, r1q);
    epilogue4_k<<<256, 256, 0, stream>>>(ymax, ymin, r1s, r1q, g4, b4, invM_edge, xbf);

    // ---- Stage 5 ----
    gemm5_mfma<<<256, 256, 0, stream>>>(xbf, w5, pmax, pmn, ps5, pq5);
    bnstat5_k<<<64, 256, 0, stream>>>(ps5, pq5, g5, b5, s_arr, t_arr);
    featreduce_k<<<64, 256, 0, stream>>>(pmax, pmn, s_arr, t_arr, feat8);
    outgemm_k<<<64, 256, 0, stream>>>(feat8, wemb, out);
}